// Round 6
// baseline (11000.118 us; speedup 1.0000x reference)
//
#include <hip/hip_runtime.h>

#define V_ 32000
#define E_ 256
#define H_ 512
#define B_ 32
#define S_ 128
#define T_ 64
#define TD_ 63        // decoder steps (T-1)
#define G3_ 1536      // 3*H
#define CATK_ 1792    // H + E + 2H
#define DIN_ 1280     // E + 2H
#define MPAD_ 2048    // padded M for fc1 MFMA

typedef __attribute__((ext_vector_type(8))) short bf16x8;
typedef __attribute__((ext_vector_type(4))) float f32x4;

__device__ inline unsigned short bf16_rne(float x) {
    unsigned u = __float_as_uint(x);
    unsigned r = u + 0x7FFFu + ((u >> 16) & 1u);
    return (unsigned short)(r >> 16);
}

// agent-scope store: write-through to coherence point (cross-XCD visible)
__device__ __forceinline__ void ato_stf(float* p, float v) {
    __hip_atomic_store(p, v, __ATOMIC_RELAXED, __HIP_MEMORY_SCOPE_AGENT);
}

// ---------------------------------------------------------------------------
// Fence-free hierarchical barrier: groups of 16 blocks + top level.
// base region layout (uints): group g cnt @ g*64, gen @ g*64+32;
// top cnt @ ngroups*64, top gen @ ngroups*64+32.
// Readers consume cross-block data at FRESH addresses (rotating buffers), so
// no cache invalidation is needed anywhere.
// ---------------------------------------------------------------------------
__device__ __forceinline__ void fast_barN(unsigned* base, int idx, unsigned ngroups)
{
    asm volatile("s_waitcnt vmcnt(0)" ::: "memory");
    __syncthreads();
    if (threadIdx.x == 0) {
        unsigned* gcnt = base + (idx >> 4) * 64;
        unsigned* ggen = gcnt + 32;
        unsigned* tcnt = base + ngroups * 64;
        unsigned* tgen = tcnt + 32;
        unsigned g0 = __hip_atomic_load(ggen, __ATOMIC_RELAXED, __HIP_MEMORY_SCOPE_AGENT);
        unsigned a  = __hip_atomic_fetch_add(gcnt, 1u, __ATOMIC_RELAXED, __HIP_MEMORY_SCOPE_AGENT);
        if (a == 15u) {
            unsigned t0 = __hip_atomic_load(tgen, __ATOMIC_RELAXED, __HIP_MEMORY_SCOPE_AGENT);
            unsigned ta = __hip_atomic_fetch_add(tcnt, 1u, __ATOMIC_RELAXED, __HIP_MEMORY_SCOPE_AGENT);
            if (ta == ngroups - 1u) {
                __hip_atomic_store(tcnt, 0u, __ATOMIC_RELAXED, __HIP_MEMORY_SCOPE_AGENT);
                __hip_atomic_store(tgen, t0 + 1u, __ATOMIC_RELAXED, __HIP_MEMORY_SCOPE_AGENT);
            } else {
                while (__hip_atomic_load(tgen, __ATOMIC_RELAXED, __HIP_MEMORY_SCOPE_AGENT) == t0)
                    __builtin_amdgcn_s_sleep(1);
            }
            __hip_atomic_store(gcnt, 0u, __ATOMIC_RELAXED, __HIP_MEMORY_SCOPE_AGENT);
            __hip_atomic_store(ggen, g0 + 1u, __ATOMIC_RELAXED, __HIP_MEMORY_SCOPE_AGENT);
        } else {
            while (__hip_atomic_load(ggen, __ATOMIC_RELAXED, __HIP_MEMORY_SCOPE_AGENT) == g0)
                __builtin_amdgcn_s_sleep(1);
        }
    }
    __syncthreads();
}

// ---------------------------------------------------------------------------
// prep: token permutations + zero encoder h slot0 + zero barrier region
// ---------------------------------------------------------------------------
__global__ __launch_bounds__(256)
void prep_kernel(const int* __restrict__ src, const int* __restrict__ tgt,
                 int* __restrict__ tokf, int* __restrict__ tokb, int* __restrict__ tokd,
                 float* __restrict__ enc_h0, unsigned* __restrict__ bars)
{
    int tid = blockIdx.x * 256 + threadIdx.x;
    if (tid < S_ * B_) {
        int s = tid >> 5, b = tid & 31;
        tokf[tid] = src[b * S_ + s];
        tokb[tid] = src[b * S_ + (S_ - 1 - s)];
    }
    if (tid < TD_ * B_) {
        int t = tid >> 5, b = tid & 31;
        tokd[tid] = tgt[b * T_ + t];
    }
    if (tid < 2 * B_ * H_) enc_h0[tid] = 0.f;   // encrot slot 0: [dir][b][k]
    if (tid < 4096) bars[tid] = 0u;
}

// ---------------------------------------------------------------------------
// write decoder embeddings into cat[:, 512:768]
// ---------------------------------------------------------------------------
__global__ __launch_bounds__(256)
void emb_cat_kernel(const int* __restrict__ tokd, const float* __restrict__ dec_emb,
                    float* __restrict__ cat)
{
    int row = blockIdx.x;          // row = t*32 + b
    int tid = threadIdx.x;         // 0..255 == E_
    cat[(size_t)row * CATK_ + H_ + tid] = dec_emb[(size_t)tokd[row] * E_ + tid];
}

// ---------------------------------------------------------------------------
// Generic fp32 GEMM (small GEMMs + fallback fc1)
// ---------------------------------------------------------------------------
template<int GATHER, int FC1MAP>
__global__ __launch_bounds__(256)
void gemm128_kernel(const float* __restrict__ A, int lda,
                    const int* __restrict__ tokens, const float* __restrict__ emb,
                    const float* __restrict__ W, int ldw,
                    const float* __restrict__ bias,
                    float* __restrict__ C, int ldc,
                    int M, int N, int K)
{
    __shared__ float As[16][132];
    __shared__ float Ws[16][132];
    (void)N;
    int tid = threadIdx.x;
    int m0 = blockIdx.y * 128, n0 = blockIdx.x * 128;
    int tx = tid & 15, ty = tid >> 4;
    float c[8][8];
#pragma unroll
    for (int i = 0; i < 8; i++)
#pragma unroll
        for (int j = 0; j < 8; j++) c[i][j] = 0.f;

    int arow = tid >> 1;
    int kq = (tid & 1) * 8;

    int am = m0 + arow; if (am >= M) am = M - 1;
    const float* arp;
    if (GATHER) arp = emb + (size_t)tokens[am] * (size_t)K;
    else        arp = A + (size_t)am * (size_t)lda;
    const float* wrp = W + (size_t)(n0 + arow) * (size_t)ldw;

    for (int kb = 0; kb < K; kb += 16) {
        __syncthreads();
        float4 a0 = *(const float4*)(arp + kb + kq);
        float4 a1 = *(const float4*)(arp + kb + kq + 4);
        float4 w0 = *(const float4*)(wrp + kb + kq);
        float4 w1 = *(const float4*)(wrp + kb + kq + 4);
        As[kq + 0][arow] = a0.x; As[kq + 1][arow] = a0.y;
        As[kq + 2][arow] = a0.z; As[kq + 3][arow] = a0.w;
        As[kq + 4][arow] = a1.x; As[kq + 5][arow] = a1.y;
        As[kq + 6][arow] = a1.z; As[kq + 7][arow] = a1.w;
        Ws[kq + 0][arow] = w0.x; Ws[kq + 1][arow] = w0.y;
        Ws[kq + 2][arow] = w0.z; Ws[kq + 3][arow] = w0.w;
        Ws[kq + 4][arow] = w1.x; Ws[kq + 5][arow] = w1.y;
        Ws[kq + 6][arow] = w1.z; Ws[kq + 7][arow] = w1.w;
        __syncthreads();
#pragma unroll
        for (int kk = 0; kk < 16; kk++) {
            float a[8], bb[8];
            *(float4*)&a[0]  = *(const float4*)&As[kk][ty * 8];
            *(float4*)&a[4]  = *(const float4*)&As[kk][ty * 8 + 4];
            *(float4*)&bb[0] = *(const float4*)&Ws[kk][tx * 8];
            *(float4*)&bb[4] = *(const float4*)&Ws[kk][tx * 8 + 4];
#pragma unroll
            for (int i = 0; i < 8; i++)
#pragma unroll
                for (int j = 0; j < 8; j++) c[i][j] += a[i] * bb[j];
        }
    }

#pragma unroll
    for (int i = 0; i < 8; i++) {
        int m = m0 + ty * 8 + i;
        if (m < M) {
            size_t rowoff;
            if (FC1MAP) { int tt = m >> 5, bb2 = m & 31; rowoff = ((size_t)bb2 * T_ + tt) * (size_t)ldc; }
            else        rowoff = (size_t)m * (size_t)ldc;
#pragma unroll
            for (int j = 0; j < 8; j += 4) {
                int n = n0 + tx * 8 + j;
                float4 v;
                v.x = c[i][j + 0] + bias[n + 0];
                v.y = c[i][j + 1] + bias[n + 1];
                v.z = c[i][j + 2] + bias[n + 2];
                v.w = c[i][j + 3] + bias[n + 3];
                *(float4*)(C + rowoff + n) = v;
            }
        }
    }
}

// ---------------------------------------------------------------------------
// PERSISTENT bi-GRU encoder: 128 blocks; h state ROTATES per step (fresh addr
// -> cached reads OK); writes via agent store. Per-direction 64-block barrier.
// Tail (after full barrier): enc_fc -> hrot slot 0 ([k*32+b]).
// ---------------------------------------------------------------------------
__global__ __launch_bounds__(256)
void enc_coop_kernel(const float* __restrict__ gxf, const float* __restrict__ gxb,
                     const float* __restrict__ Whh_f, const float* __restrict__ bhh_f,
                     const float* __restrict__ Whh_b, const float* __restrict__ bhh_b,
                     float* __restrict__ encrot, float* __restrict__ enc_bt,
                     const float* __restrict__ fcW, const float* __restrict__ fcb,
                     float* __restrict__ hT0, unsigned* __restrict__ bars)
{
    const int bid = blockIdx.x;
    const int dir = bid >> 6, bh = (bid >> 5) & 1, kc = bid & 31;
    const int tid = threadIdx.x;
    const int bl = tid & 15, kl = tid >> 4;
    const int b = bh * 16 + bl, k = kc * 16 + kl;
    const float* Whh = dir ? Whh_b : Whh_f;
    const float* bhhp = dir ? bhh_b : bhh_f;
    const float* gx  = dir ? gxb : gxf;
    __shared__ float hL[16 * 516];
    const float* wr = Whh + (size_t)k * H_;
    const float* wz = Whh + (size_t)(H_ + k) * H_;
    const float* wn = Whh + (size_t)(2 * H_ + k) * H_;
    const float b_r = bhhp[k], b_z = bhhp[H_ + k], b_n = bhhp[2 * H_ + k];
    unsigned* dbar = bars + dir * 512;
    const int idx = bid & 63;

    for (int t = 0; t < S_; ++t) {
        const float* hin = encrot + (size_t)t * (2 * B_ * H_) + (size_t)dir * (B_ * H_);
        float* hout = encrot + (size_t)(t + 1) * (2 * B_ * H_) + (size_t)dir * (B_ * H_);
        const float* hsrc = hin + (size_t)bh * 16 * H_;
        for (int i = tid * 4; i < 16 * H_; i += 1024) {
            int r = i >> 9, cix = i & 511;
            *(float4*)&hL[r * 516 + cix] = *(const float4*)(hsrc + i);   // cached
        }
        __syncthreads();
        float ar = 0.f, az = 0.f, an = 0.f;
        const float* hv = &hL[bl * 516];
#pragma unroll 4
        for (int j = 0; j < H_; j += 4) {
            float4 h4 = *(const float4*)(hv + j);
            float4 r4 = *(const float4*)(wr + j);
            float4 z4 = *(const float4*)(wz + j);
            float4 n4 = *(const float4*)(wn + j);
            ar += h4.x * r4.x + h4.y * r4.y + h4.z * r4.z + h4.w * r4.w;
            az += h4.x * z4.x + h4.y * z4.y + h4.z * z4.z + h4.w * z4.w;
            an += h4.x * n4.x + h4.y * n4.y + h4.z * n4.z + h4.w * n4.w;
        }
        const float* gxr = gx + ((size_t)t * B_ + b) * G3_;
        float xr = gxr[k], xz = gxr[H_ + k], xn = gxr[2 * H_ + k];
        float rg = 1.f / (1.f + expf(-(xr + ar + b_r)));
        float zg = 1.f / (1.f + expf(-(xz + az + b_z)));
        float ng = tanhf(xn + rg * (an + b_n));
        float hp = hL[bl * 516 + k];
        float h2 = (1.f - zg) * ng + zg * hp;
        ato_stf(hout + (size_t)b * H_ + k, h2);
        int s_out = dir ? (S_ - 1 - t) : t;
        enc_bt[((size_t)b * S_ + s_out) * (2 * H_) + dir * H_ + k] = h2;
        fast_barN(dbar, idx, 4);
    }
    fast_barN(bars + 1024, bid, 8);    // full barrier: both dirs done

    // tail: hidden = tanh([hf,hb] @ fcW.T + fcb) -> hT0[k*32+b]
    {
        const int b2 = bid & 31, ih = bid >> 5;   // ih in 0..3
        float* hc = hL;
        const float* hfin = encrot + (size_t)S_ * (2 * B_ * H_);
        const float* hf  = hfin + (size_t)b2 * H_;                    // dir 0
        const float* hbk = hfin + (size_t)B_ * H_ + (size_t)b2 * H_;  // dir 1
        for (int i = tid; i < H_; i += 256) { hc[i] = hf[i]; hc[H_ + i] = hbk[i]; }
        __syncthreads();
        if (tid < 128) {
            int i = ih * 128 + tid;
            const float* w = fcW + (size_t)i * (2 * H_);
            float acc = 0.f;
            for (int j = 0; j < 2 * H_; j += 4) {
                float4 a4 = *(const float4*)&hc[j];
                float4 w4 = *(const float4*)(w + j);
                acc += a4.x * w4.x + a4.y * w4.y + a4.z * w4.z + a4.w * w4.w;
            }
            hT0[(size_t)i * B_ + b2] = tanhf(acc + fcb[i]);
        }
    }
}

// ---------------------------------------------------------------------------
// PERSISTENT attention decoder: 128 blocks, TWO phases/step.
// Phase1: blocks 0..31 = full attention for batch b (incl. own hWh);
//         blocks 32..127 = 16 rows each of ghh = Whh·h + bhh.
// Phase2: all blocks: xr/xz/xn = Wih·w for kbase..+3 + gate finish.
// Comm buffers (h, wT, ghh) rotate per step: agent stores, cached reads.
// Layouts: h [k*32+b], wT [c*32+b], ghh [r*32+b].
// ---------------------------------------------------------------------------
__global__ __launch_bounds__(256)
void dec_coop_kernel(const float* __restrict__ attn_W, const float* __restrict__ attn_v,
                     const float* __restrict__ enc_projB, const float* __restrict__ enc_bt,
                     const int* __restrict__ src,
                     const float* __restrict__ dWhh, const float* __restrict__ dbhh,
                     const float* __restrict__ dWih, const float* __restrict__ gx_emb,
                     float* __restrict__ cat, float* __restrict__ hrot,
                     float* __restrict__ wrot, float* __restrict__ grot,
                     unsigned* __restrict__ bars)
{
    const int bid = blockIdx.x, tid = threadIdx.x;
    __shared__ float smem[4352];   // union: part[256][17] | attn {hcol,vL,hwh,aL,red}
    const int b = tid & 31, cc = tid >> 5;
    const int kbase = bid * 4;
    const float* wir0 = dWih + (size_t)(kbase + 0) * DIN_ + E_;
    const float* wir1 = dWih + (size_t)(kbase + 1) * DIN_ + E_;
    const float* wir2 = dWih + (size_t)(kbase + 2) * DIN_ + E_;
    const float* wir3 = dWih + (size_t)(kbase + 3) * DIN_ + E_;
    const float* wiz0 = dWih + (size_t)(H_ + kbase + 0) * DIN_ + E_;
    const float* wiz1 = dWih + (size_t)(H_ + kbase + 1) * DIN_ + E_;
    const float* wiz2 = dWih + (size_t)(H_ + kbase + 2) * DIN_ + E_;
    const float* wiz3 = dWih + (size_t)(H_ + kbase + 3) * DIN_ + E_;
    const float* win0 = dWih + (size_t)(2 * H_ + kbase + 0) * DIN_ + E_;
    const float* win1 = dWih + (size_t)(2 * H_ + kbase + 1) * DIN_ + E_;
    const float* win2 = dWih + (size_t)(2 * H_ + kbase + 2) * DIN_ + E_;
    const float* win3 = dWih + (size_t)(2 * H_ + kbase + 3) * DIN_ + E_;

    for (int t = 0; t < TD_; ++t) {
        const float* h_t = hrot + (size_t)t * (H_ * B_);
        float* h_n = hrot + (size_t)(t + 1) * (H_ * B_);
        float* wT = wrot + (size_t)t * (2 * H_ * B_);
        float* gh = grot + (size_t)t * (G3_ * B_);
        float* cat_t = cat + (size_t)t * B_ * CATK_;

        // ================= Phase 1 =================
        if (bid < 32) {
            const int ab = bid;
            float* hcol = smem;          // 512
            float* vL   = smem + 512;    // 512
            float* hwh  = smem + 1024;   // 512
            float* aL   = smem + 1536;   // 128
            float* red  = smem + 1664;   // 2
            for (int i = tid; i < H_; i += 256) {
                hcol[i] = h_t[(size_t)i * B_ + ab];   // cached
                vL[i]   = attn_v[i];
            }
            __syncthreads();
            // hWh rows 2tid, 2tid+1
            {
                const float* w0p = attn_W + (size_t)(2 * tid) * G3_;
                const float* w1p = w0p + G3_;
                float a0 = 0.f, a1 = 0.f;
                for (int j = 0; j < H_; j += 4) {
                    float4 h4 = *(const float4*)&hcol[j];
                    float4 x0 = *(const float4*)(w0p + j);
                    float4 x1 = *(const float4*)(w1p + j);
                    a0 += h4.x * x0.x + h4.y * x0.y + h4.z * x0.z + h4.w * x0.w;
                    a1 += h4.x * x1.x + h4.y * x1.y + h4.z * x1.z + h4.w * x1.w;
                }
                hwh[2 * tid] = a0; hwh[2 * tid + 1] = a1;
            }
            __syncthreads();
            // scores
            int wv = tid >> 6, lane = tid & 63;
            for (int so = 0; so < 32; so++) {
                int s = so * 4 + wv;
                const float* pr = enc_projB + ((size_t)ab * S_ + s) * H_;
                float acc = 0.f;
#pragma unroll
                for (int u = 0; u < 8; u++) {
                    int hh = u * 64 + lane;
                    float x = hwh[hh] + pr[hh];
                    float e2 = __expf(2.f * x);
                    acc += vL[hh] * (1.f - 2.f / (e2 + 1.f));
                }
#pragma unroll
                for (int off = 1; off < 64; off <<= 1) acc += __shfl_xor(acc, off);
                if (lane == 0) aL[s] = acc;
            }
            __syncthreads();
            if (tid < S_) aL[tid] = (src[ab * S_ + tid] != 0) ? aL[tid] : -1e10f;
            __syncthreads();
            if (tid < 64) {
                float m = fmaxf(aL[tid], aL[tid + 64]);
#pragma unroll
                for (int off = 1; off < 64; off <<= 1) m = fmaxf(m, __shfl_xor(m, off));
                if (tid == 0) red[0] = m;
            }
            __syncthreads();
            if (tid < S_) aL[tid] = expf(aL[tid] - red[0]);
            __syncthreads();
            if (tid < 64) {
                float sv = aL[tid] + aL[tid + 64];
#pragma unroll
                for (int off = 1; off < 64; off <<= 1) sv += __shfl_xor(sv, off);
                if (tid == 0) red[1] = sv;
            }
            __syncthreads();
            if (tid < S_) aL[tid] = aL[tid] / red[1];
            __syncthreads();
            const float* eb = enc_bt + (size_t)ab * S_ * (2 * H_) + tid * 4;
            float w0 = 0, w1 = 0, w2 = 0, w3 = 0;
            for (int s = 0; s < S_; s++) {
                float a = aL[s];
                float4 v = *(const float4*)(eb + (size_t)s * (2 * H_));
                w0 += a * v.x; w1 += a * v.y; w2 += a * v.z; w3 += a * v.w;
            }
            float4 outv; outv.x = w0; outv.y = w1; outv.z = w2; outv.w = w3;
            *(float4*)(cat_t + (size_t)ab * CATK_ + (H_ + E_) + tid * 4) = outv;
            ato_stf(wT + (size_t)(tid * 4 + 0) * B_ + ab, w0);
            ato_stf(wT + (size_t)(tid * 4 + 1) * B_ + ab, w1);
            ato_stf(wT + (size_t)(tid * 4 + 2) * B_ + ab, w2);
            ato_stf(wT + (size_t)(tid * 4 + 3) * B_ + ab, w3);
        } else {
            // ghh rows r0base..+15; thread (b, cc): partial over 64-j chunk
            const int r0base = (bid - 32) * 16;
            float acc[16];
#pragma unroll
            for (int r = 0; r < 16; ++r) acc[r] = 0.f;
            for (int jj = 0; jj < 16; ++jj) {
                int j = cc * 64 + jj * 4;
                float h0 = h_t[(size_t)(j + 0) * B_ + b];   // cached, coalesced over b
                float h1 = h_t[(size_t)(j + 1) * B_ + b];
                float h2v = h_t[(size_t)(j + 2) * B_ + b];
                float h3 = h_t[(size_t)(j + 3) * B_ + b];
#pragma unroll
                for (int r = 0; r < 16; ++r) {
                    float4 w = *(const float4*)(dWhh + (size_t)(r0base + r) * H_ + j);
                    acc[r] += h0 * w.x + h1 * w.y + h2v * w.z + h3 * w.w;
                }
            }
            float* part = smem;   // [256][17]
#pragma unroll
            for (int r = 0; r < 16; ++r) part[tid * 17 + r] = acc[r];
            __syncthreads();
            for (int o = tid; o < 512; o += 256) {
                int r = o >> 5, bb = o & 31;
                float s = 0.f;
#pragma unroll
                for (int c2 = 0; c2 < 8; ++c2) s += part[(c2 * 32 + bb) * 17 + r];
                ato_stf(gh + (size_t)(r0base + r) * B_ + bb, s + dbhh[r0base + r]);
            }
        }
        fast_barN(bars, bid, 8);

        // ================= Phase 2 =================
        {
            float s[12];
#pragma unroll
            for (int i = 0; i < 12; i++) s[i] = 0.f;
            const int c0 = cc * 128;
            for (int c = c0; c < c0 + 128; ++c) {
                float wv = wT[(size_t)c * B_ + b];   // cached, coalesced over b
                s[0]  += wv * wir0[c]; s[1]  += wv * wiz0[c]; s[2]  += wv * win0[c];
                s[3]  += wv * wir1[c]; s[4]  += wv * wiz1[c]; s[5]  += wv * win1[c];
                s[6]  += wv * wir2[c]; s[7]  += wv * wiz2[c]; s[8]  += wv * win2[c];
                s[9]  += wv * wir3[c]; s[10] += wv * wiz3[c]; s[11] += wv * win3[c];
            }
            float* part = smem;   // [256][13]
#pragma unroll
            for (int i = 0; i < 12; i++) part[tid * 13 + i] = s[i];
            __syncthreads();
            if (tid < 128) {
                int bb = tid & 31, k4 = tid >> 5;
                int k = kbase + k4;
                float xr = 0.f, xz = 0.f, xn = 0.f;
#pragma unroll
                for (int c2 = 0; c2 < 8; ++c2) {
                    int pi = (c2 * 32 + bb) * 13 + k4 * 3;
                    xr += part[pi + 0]; xz += part[pi + 1]; xn += part[pi + 2];
                }
                float hr = gh[(size_t)k * B_ + bb];
                float hz = gh[(size_t)(H_ + k) * B_ + bb];
                float hn = gh[(size_t)(2 * H_ + k) * B_ + bb];
                const float* gxe = gx_emb + ((size_t)t * B_ + bb) * G3_;
                float rg = 1.f / (1.f + expf(-(gxe[k] + xr + hr)));
                float zg = 1.f / (1.f + expf(-(gxe[H_ + k] + xz + hz)));
                float ng = tanhf(gxe[2 * H_ + k] + xn + rg * hn);
                float hp = h_t[(size_t)k * B_ + bb];
                float h2 = (1.f - zg) * ng + zg * hp;
                ato_stf(h_n + (size_t)k * B_ + bb, h2);
                cat_t[(size_t)bb * CATK_ + k] = h2;
            }
        }
        fast_barN(bars, bid, 8);
    }
}

// ---------------------------------------------------------------------------
// split cat (fp32 [2016][1792]) into bf16 hi/lo, padded to 2048 rows (zeros)
// ---------------------------------------------------------------------------
__global__ __launch_bounds__(256)
void splitA_kernel(const float* __restrict__ cat,
                   unsigned short* __restrict__ Ahi, unsigned short* __restrict__ Alo)
{
    size_t i4 = ((size_t)blockIdx.x * 256 + threadIdx.x) * 4;
    if (i4 >= (size_t)MPAD_ * CATK_) return;
    size_t row = i4 / CATK_;
    float4 v;
    if (row < (size_t)TD_ * B_) v = *(const float4*)(cat + i4);
    else { v.x = v.y = v.z = v.w = 0.f; }
    float f[4] = {v.x, v.y, v.z, v.w};
    unsigned short h[4], l[4];
#pragma unroll
    for (int j = 0; j < 4; j++) {
        h[j] = bf16_rne(f[j]);
        float hf = __uint_as_float((unsigned)h[j] << 16);
        l[j] = bf16_rne(f[j] - hf);
    }
    *(ushort4*)(Ahi + i4) = make_ushort4(h[0], h[1], h[2], h[3]);
    *(ushort4*)(Alo + i4) = make_ushort4(l[0], l[1], l[2], l[3]);
}

// ---------------------------------------------------------------------------
// fc1 via split-bf16 MFMA (hh + hl + lh): fp32-accurate logits.
// ---------------------------------------------------------------------------
__global__ __launch_bounds__(256)
void fc1_mfma_kernel(const unsigned short* __restrict__ Ahi,
                     const unsigned short* __restrict__ Alo,
                     const float* __restrict__ W,
                     const float* __restrict__ bias,
                     float* __restrict__ C)
{
    __shared__ unsigned short lA[2][128][40];
    __shared__ unsigned short lW[2][128][40];
    const int tid = threadIdx.x;
    const int m0 = blockIdx.x * 128, n0 = blockIdx.y * 128;
    const int w = tid >> 6, lane = tid & 63;
    const int wm = w >> 1, wn = w & 1;
    const int frow = lane & 15, fk = (lane >> 4) * 8;

    f32x4 acc[4][4];
#pragma unroll
    for (int mi = 0; mi < 4; mi++)
#pragma unroll
        for (int ni = 0; ni < 4; ni++) acc[mi][ni] = (f32x4){0.f, 0.f, 0.f, 0.f};

    const int srow = tid >> 1;
    const int skq = (tid & 1) * 16;

    const unsigned short* gAhi = Ahi + (size_t)(m0 + srow) * CATK_ + skq;
    const unsigned short* gAlo = Alo + (size_t)(m0 + srow) * CATK_ + skq;
    const float*          gW   = W   + (size_t)(n0 + srow) * CATK_ + skq;

    int4 rAh0, rAh1, rAl0, rAl1;
    float4 rW0, rW1, rW2, rW3;

#define FC1_LOAD(kb)                                        \
    do {                                                    \
        rAh0 = *(const int4*)(gAhi + (kb));                 \
        rAh1 = *(const int4*)(gAhi + (kb) + 8);             \
        rAl0 = *(const int4*)(gAlo + (kb));                 \
        rAl1 = *(const int4*)(gAlo + (kb) + 8);             \
        rW0  = *(const float4*)(gW + (kb));                 \
        rW1  = *(const float4*)(gW + (kb) + 4);             \
        rW2  = *(const float4*)(gW + (kb) + 8);             \
        rW3  = *(const float4*)(gW + (kb) + 12);            \
    } while (0)

    FC1_LOAD(0);

    for (int kb = 0; kb < CATK_; kb += 32) {
        __syncthreads();
        *(int4*)&lA[0][srow][skq]     = rAh0;
        *(int4*)&lA[0][srow][skq + 8] = rAh1;
        *(int4*)&lA[1][srow][skq]     = rAl0;
        *(int4*)&lA[1][srow][skq + 8] = rAl1;
        {
            float f[16] = {rW0.x, rW0.y, rW0.z, rW0.w, rW1.x, rW1.y, rW1.z, rW1.w,
                           rW2.x, rW2.y, rW2.z, rW2.w, rW3.x, rW3.y, rW3.z, rW3.w};
            unsigned hp[8], lp[8];
#pragma unroll
            for (int j = 0; j < 8; j++) {
                float x0 = f[2 * j], x1 = f[2 * j + 1];
                unsigned short h0 = bf16_rne(x0), h1 = bf16_rne(x1);
                float r0 = x0 - __uint_as_float((unsigned)h0 << 16);
                float r1 = x1 - __uint_as_float((unsigned)h1 << 16);
                hp[j] = (unsigned)h0 | ((unsigned)h1 << 16);
                lp[j] = (unsigned)bf16_rne(r0) | ((unsigned)bf16_rne(r1) << 16);
            }
            *(int4*)&lW[0][srow][skq]     = make_int4(hp[0], hp[1], hp[2], hp[3]);
            *(int4*)&lW[0][srow][skq + 8] = make_int4(hp[4], hp[5], hp[6], hp[7]);
            *(int4*)&lW[1][srow][skq]     = make_int4(lp[0], lp[1], lp[2], lp[3]);
            *(int4*)&lW[1][srow][skq + 8] = make_int4(lp[4], lp[5], lp[6], lp[7]);
        }
        __syncthreads();
        if (kb + 32 < CATK_) FC1_LOAD(kb + 32);

        bf16x8 a[2][4];
#pragma unroll
        for (int mi = 0; mi < 4; mi++) {
            int r = wm * 64 + mi * 16 + frow;
            a[0][mi] = *(const bf16x8*)&lA[0][r][fk];
            a[1][mi] = *(const bf16x8*)&lA[1][r][fk];
        }
#pragma unroll
        for (int ni = 0; ni < 4; ni++) {
            int r = wn * 64 + ni * 16 + frow;
            bf16x8 bh = *(const bf16x8*)&lW[0][r][fk];
            bf16x8 bl = *(const bf16x8*)&lW[1][r][fk];
#pragma unroll
            for (int mi = 0; mi < 4; mi++) {
                acc[mi][ni] = __builtin_amdgcn_mfma_f32_16x16x32_bf16(a[0][mi], bh, acc[mi][ni], 0, 0, 0);
                acc[mi][ni] = __builtin_amdgcn_mfma_f32_16x16x32_bf16(a[1][mi], bh, acc[mi][ni], 0, 0, 0);
                acc[mi][ni] = __builtin_amdgcn_mfma_f32_16x16x32_bf16(a[0][mi], bl, acc[mi][ni], 0, 0, 0);
            }
        }
    }
#undef FC1_LOAD

#pragma unroll
    for (int ni = 0; ni < 4; ni++) {
        int col = n0 + wn * 64 + ni * 16 + frow;
        float bc = bias[col];
#pragma unroll
        for (int mi = 0; mi < 4; mi++) {
            int mbase = m0 + wm * 64 + mi * 16 + (lane >> 4) * 4;
            f32x4 v = acc[mi][ni];
#pragma unroll
            for (int r = 0; r < 4; r++) {
                int m = mbase + r;
                if (m < TD_ * B_) {
                    int tt = m >> 5, bb2 = m & 31;
                    C[((size_t)bb2 * T_ + tt) * V_ + col] = v[r] + bc;
                }
            }
        }
    }
}

// ---------------------------------------------------------------------------
__global__ __launch_bounds__(256)
void argmax_kernel(const float* __restrict__ outp, float* __restrict__ preds)
{
    int row = blockIdx.x;
    int t = row >> 5, b = row & 31;
    const float* p = outp + ((size_t)b * T_ + t) * V_;
    int tid = threadIdx.x;
    float best = -3.4e38f; int bi = V_;
    for (int i = tid; i < V_; i += 256) {
        float v = p[i];
        if (v > best) { best = v; bi = i; }
    }
    __shared__ float bv[256];
    __shared__ int bidx[256];
    bv[tid] = best; bidx[tid] = bi;
    __syncthreads();
    for (int off = 128; off > 0; off >>= 1) {
        if (tid < off) {
            float v2 = bv[tid + off]; int i2 = bidx[tid + off];
            if (v2 > bv[tid] || (v2 == bv[tid] && i2 < bidx[tid])) { bv[tid] = v2; bidx[tid] = i2; }
        }
        __syncthreads();
    }
    if (tid == 0) preds[(size_t)b * T_ + t] = (float)bidx[0];
}

// ---------------------------------------------------------------------------
__global__ __launch_bounds__(256)
void zero_tail_kernel(float* __restrict__ outp, float* __restrict__ preds)
{
    int tid = blockIdx.x * 256 + threadIdx.x;
    if (tid < B_ * V_) {
        int b = tid / V_;
        int c = tid % V_;
        outp[((size_t)b * T_ + (T_ - 1)) * V_ + c] = 0.f;
    }
    if (tid < B_) preds[(size_t)tid * T_ + (T_ - 1)] = 0.f;
}

// ---------------------------------------------------------------------------
extern "C" void kernel_launch(void* const* d_in, const int* in_sizes, int n_in,
                              void* d_out, int out_size, void* d_ws, size_t ws_size,
                              hipStream_t stream)
{
    (void)in_sizes; (void)n_in; (void)out_size;
    const int*   src     = (const int*)d_in[0];
    const int*   tgt     = (const int*)d_in[1];
    const float* enc_emb = (const float*)d_in[2];
    const float* Wih_f   = (const float*)d_in[3];
    const float* Whh_f   = (const float*)d_in[4];
    const float* bih_f   = (const float*)d_in[5];
    const float* bhh_f   = (const float*)d_in[6];
    const float* Wih_b   = (const float*)d_in[7];
    const float* Whh_b   = (const float*)d_in[8];
    const float* bih_b   = (const float*)d_in[9];
    const float* bhh_b   = (const float*)d_in[10];
    const float* fcW     = (const float*)d_in[11];
    const float* fcb     = (const float*)d_in[12];
    const float* dec_emb = (const float*)d_in[13];
    const float* attn_W  = (const float*)d_in[14];
    const float* attn_b  = (const float*)d_in[15];
    const float* attn_v  = (const float*)d_in[16];
    const float* dWih    = (const float*)d_in[17];
    const float* dWhh    = (const float*)d_in[18];
    const float* dbih    = (const float*)d_in[19];
    const float* dbhh    = (const float*)d_in[20];
    const float* fc1W    = (const float*)d_in[21];
    const float* fc1b    = (const float*)d_in[22];
    (void)dbih;

    // ws layout
    float* ws     = (float*)d_ws;
    float* cat    = ws;                                  // 3,612,672 f
    float* gx_emb = cat + (size_t)TD_ * B_ * CATK_;      // 3,096,576 f
    int*   tokf   = (int*)(gx_emb + (size_t)TD_ * B_ * G3_);
    int*   tokb   = tokf + 4096;
    int*   tokd   = tokb + 4096;
    unsigned* bars = (unsigned*)(tokd + 4096);           // 4096 u, 256B-aligned
    unsigned short* Ahi = (unsigned short*)(bars + 4096);
    unsigned short* Alo = Ahi + (size_t)MPAD_ * CATK_;
    size_t ws_req = (size_t)((char*)(Alo + (size_t)MPAD_ * CATK_) - (char*)d_ws);
    const bool use_mfma = (ws_size >= ws_req);

    // d_out scratch (fully overwritten by fc1 + zero_tail afterwards)
    float* dout      = (float*)d_out;
    float* gxf       = dout;                                        // 6,291,456
    float* gxb       = gxf + (size_t)S_ * B_ * G3_;                 // 6,291,456
    float* enc_bt    = gxb + (size_t)S_ * B_ * G3_;                 // 4,194,304
    float* enc_projB = enc_bt + (size_t)B_ * S_ * 2 * H_;           // 2,097,152
    float* hrot      = enc_projB + (size_t)B_ * S_ * H_;            // 64 x 16,384
    float* wrot      = hrot + (size_t)64 * H_ * B_;                 // 64 x 32,768
    float* grot      = wrot + (size_t)64 * 2 * H_ * B_;             // 64 x 49,152
    float* encrot    = grot + (size_t)64 * G3_ * B_;                // 129 x 32,768
    float* preds     = dout + (size_t)B_ * T_ * V_;

    dim3 thr(256);

    hipLaunchKernelGGL(prep_kernel, dim3(256), thr, 0, stream,
                       src, tgt, tokf, tokb, tokd, encrot, bars);
    hipLaunchKernelGGL(emb_cat_kernel, dim3(TD_ * B_), thr, 0, stream, tokd, dec_emb, cat);

    hipLaunchKernelGGL((gemm128_kernel<1, 0>), dim3(G3_ / 128, (S_ * B_) / 128), thr, 0, stream,
                       (const float*)nullptr, 0, tokf, enc_emb, Wih_f, E_, bih_f,
                       gxf, G3_, S_ * B_, G3_, E_);
    hipLaunchKernelGGL((gemm128_kernel<1, 0>), dim3(G3_ / 128, (S_ * B_) / 128), thr, 0, stream,
                       (const float*)nullptr, 0, tokb, enc_emb, Wih_b, E_, bih_b,
                       gxb, G3_, S_ * B_, G3_, E_);

    // encoder recurrence + enc_fc in ONE launch
    hipLaunchKernelGGL(enc_coop_kernel, dim3(128), thr, 0, stream,
                       gxf, gxb, Whh_f, bhh_f, Whh_b, bhh_b, encrot, enc_bt,
                       fcW, fcb, hrot /* h slot 0 */, bars);

    hipLaunchKernelGGL((gemm128_kernel<0, 0>), dim3(H_ / 128, (B_ * S_) / 128), thr, 0, stream,
                       enc_bt, 2 * H_, (const int*)nullptr, (const float*)nullptr,
                       attn_W + H_, G3_, attn_b, enc_projB, H_, B_ * S_, H_, 2 * H_);

    hipLaunchKernelGGL((gemm128_kernel<1, 0>), dim3(G3_ / 128, (TD_ * B_ + 127) / 128), thr, 0, stream,
                       (const float*)nullptr, 0, tokd, dec_emb, dWih, DIN_, dbih,
                       gx_emb, G3_, TD_ * B_, G3_, E_);

    // decoder recurrence in ONE launch
    hipLaunchKernelGGL(dec_coop_kernel, dim3(128), thr, 0, stream,
                       attn_W, attn_v, enc_projB, enc_bt, src,
                       dWhh, dbhh, dWih, gx_emb, cat, hrot, wrot, grot,
                       bars + 2048);

    if (use_mfma) {
        hipLaunchKernelGGL(splitA_kernel, dim3((MPAD_ * CATK_ / 4 + 255) / 256), thr, 0, stream,
                           cat, Ahi, Alo);
        hipLaunchKernelGGL(fc1_mfma_kernel, dim3(MPAD_ / 128, V_ / 128), thr, 0, stream,
                           Ahi, Alo, fc1W, fc1b, dout);
    } else {
        hipLaunchKernelGGL((gemm128_kernel<0, 1>), dim3(V_ / 128, (TD_ * B_ + 127) / 128), thr, 0, stream,
                           cat, CATK_, (const int*)nullptr, (const float*)nullptr,
                           fc1W, CATK_, fc1b, dout, V_, TD_ * B_, V_, CATK_);
    }

    hipLaunchKernelGGL(argmax_kernel, dim3(TD_ * B_), thr, 0, stream, dout, preds);
    hipLaunchKernelGGL(zero_tail_kernel, dim3((B_ * V_ + 255) / 256), thr, 0, stream, dout, preds);
}

// Round 7
// 10471.677 us; speedup vs baseline: 1.0505x; 1.0505x over previous
//
#include <hip/hip_runtime.h>

#define V_ 32000
#define E_ 256
#define H_ 512
#define B_ 32
#define S_ 128
#define T_ 64
#define TD_ 63        // decoder steps (T-1)
#define G3_ 1536      // 3*H
#define CATK_ 1792    // H + E + 2H
#define DIN_ 1280     // E + 2H
#define MPAD_ 2048    // padded M for fc1 MFMA

typedef __attribute__((ext_vector_type(8))) short bf16x8;
typedef __attribute__((ext_vector_type(4))) float f32x4;

__device__ inline unsigned short bf16_rne(float x) {
    unsigned u = __float_as_uint(x);
    unsigned r = u + 0x7FFFu + ((u >> 16) & 1u);
    return (unsigned short)(r >> 16);
}

// agent-scope store: write-through to coherence point (cross-XCD visible).
// Readers use PLAIN CACHED loads at FRESH (rotating) addresses - verified r6.
__device__ __forceinline__ void ato_stf(float* p, float v) {
    __hip_atomic_store(p, v, __ATOMIC_RELAXED, __HIP_MEMORY_SCOPE_AGENT);
}

// ---------------------------------------------------------------------------
// Fence-free hierarchical barrier: groups of 16 blocks + top level.
// ---------------------------------------------------------------------------
__device__ __forceinline__ void fast_barN(unsigned* base, int idx, unsigned ngroups)
{
    asm volatile("s_waitcnt vmcnt(0)" ::: "memory");
    __syncthreads();
    if (threadIdx.x == 0) {
        unsigned* gcnt = base + (idx >> 4) * 64;
        unsigned* ggen = gcnt + 32;
        unsigned* tcnt = base + ngroups * 64;
        unsigned* tgen = tcnt + 32;
        unsigned g0 = __hip_atomic_load(ggen, __ATOMIC_RELAXED, __HIP_MEMORY_SCOPE_AGENT);
        unsigned a  = __hip_atomic_fetch_add(gcnt, 1u, __ATOMIC_RELAXED, __HIP_MEMORY_SCOPE_AGENT);
        if (a == 15u) {
            unsigned t0 = __hip_atomic_load(tgen, __ATOMIC_RELAXED, __HIP_MEMORY_SCOPE_AGENT);
            unsigned ta = __hip_atomic_fetch_add(tcnt, 1u, __ATOMIC_RELAXED, __HIP_MEMORY_SCOPE_AGENT);
            if (ta == ngroups - 1u) {
                __hip_atomic_store(tcnt, 0u, __ATOMIC_RELAXED, __HIP_MEMORY_SCOPE_AGENT);
                __hip_atomic_store(tgen, t0 + 1u, __ATOMIC_RELAXED, __HIP_MEMORY_SCOPE_AGENT);
            } else {
                while (__hip_atomic_load(tgen, __ATOMIC_RELAXED, __HIP_MEMORY_SCOPE_AGENT) == t0)
                    __builtin_amdgcn_s_sleep(1);
            }
            __hip_atomic_store(gcnt, 0u, __ATOMIC_RELAXED, __HIP_MEMORY_SCOPE_AGENT);
            __hip_atomic_store(ggen, g0 + 1u, __ATOMIC_RELAXED, __HIP_MEMORY_SCOPE_AGENT);
        } else {
            while (__hip_atomic_load(ggen, __ATOMIC_RELAXED, __HIP_MEMORY_SCOPE_AGENT) == g0)
                __builtin_amdgcn_s_sleep(1);
        }
    }
    __syncthreads();
}

// ---------------------------------------------------------------------------
__global__ __launch_bounds__(256)
void prep_kernel(const int* __restrict__ src, const int* __restrict__ tgt,
                 int* __restrict__ tokf, int* __restrict__ tokb, int* __restrict__ tokd,
                 float* __restrict__ enc_h0, unsigned* __restrict__ bars)
{
    int tid = blockIdx.x * 256 + threadIdx.x;
    if (tid < S_ * B_) {
        int s = tid >> 5, b = tid & 31;
        tokf[tid] = src[b * S_ + s];
        tokb[tid] = src[b * S_ + (S_ - 1 - s)];
    }
    if (tid < TD_ * B_) {
        int t = tid >> 5, b = tid & 31;
        tokd[tid] = tgt[b * T_ + t];
    }
    if (tid < 2 * B_ * H_) enc_h0[tid] = 0.f;   // encrot slot 0
    if (tid < 4096) bars[tid] = 0u;
}

// ---------------------------------------------------------------------------
__global__ __launch_bounds__(256)
void emb_cat_kernel(const int* __restrict__ tokd, const float* __restrict__ dec_emb,
                    float* __restrict__ cat)
{
    int row = blockIdx.x;          // row = t*32 + b
    int tid = threadIdx.x;         // 0..255 == E_
    cat[(size_t)row * CATK_ + H_ + tid] = dec_emb[(size_t)tokd[row] * E_ + tid];
}

// ---------------------------------------------------------------------------
template<int GATHER, int FC1MAP>
__global__ __launch_bounds__(256)
void gemm128_kernel(const float* __restrict__ A, int lda,
                    const int* __restrict__ tokens, const float* __restrict__ emb,
                    const float* __restrict__ W, int ldw,
                    const float* __restrict__ bias,
                    float* __restrict__ C, int ldc,
                    int M, int N, int K)
{
    __shared__ float As[16][132];
    __shared__ float Ws[16][132];
    (void)N;
    int tid = threadIdx.x;
    int m0 = blockIdx.y * 128, n0 = blockIdx.x * 128;
    int tx = tid & 15, ty = tid >> 4;
    float c[8][8];
#pragma unroll
    for (int i = 0; i < 8; i++)
#pragma unroll
        for (int j = 0; j < 8; j++) c[i][j] = 0.f;

    int arow = tid >> 1;
    int kq = (tid & 1) * 8;

    int am = m0 + arow; if (am >= M) am = M - 1;
    const float* arp;
    if (GATHER) arp = emb + (size_t)tokens[am] * (size_t)K;
    else        arp = A + (size_t)am * (size_t)lda;
    const float* wrp = W + (size_t)(n0 + arow) * (size_t)ldw;

    for (int kb = 0; kb < K; kb += 16) {
        __syncthreads();
        float4 a0 = *(const float4*)(arp + kb + kq);
        float4 a1 = *(const float4*)(arp + kb + kq + 4);
        float4 w0 = *(const float4*)(wrp + kb + kq);
        float4 w1 = *(const float4*)(wrp + kb + kq + 4);
        As[kq + 0][arow] = a0.x; As[kq + 1][arow] = a0.y;
        As[kq + 2][arow] = a0.z; As[kq + 3][arow] = a0.w;
        As[kq + 4][arow] = a1.x; As[kq + 5][arow] = a1.y;
        As[kq + 6][arow] = a1.z; As[kq + 7][arow] = a1.w;
        Ws[kq + 0][arow] = w0.x; Ws[kq + 1][arow] = w0.y;
        Ws[kq + 2][arow] = w0.z; Ws[kq + 3][arow] = w0.w;
        Ws[kq + 4][arow] = w1.x; Ws[kq + 5][arow] = w1.y;
        Ws[kq + 6][arow] = w1.z; Ws[kq + 7][arow] = w1.w;
        __syncthreads();
#pragma unroll
        for (int kk = 0; kk < 16; kk++) {
            float a[8], bb[8];
            *(float4*)&a[0]  = *(const float4*)&As[kk][ty * 8];
            *(float4*)&a[4]  = *(const float4*)&As[kk][ty * 8 + 4];
            *(float4*)&bb[0] = *(const float4*)&Ws[kk][tx * 8];
            *(float4*)&bb[4] = *(const float4*)&Ws[kk][tx * 8 + 4];
#pragma unroll
            for (int i = 0; i < 8; i++)
#pragma unroll
                for (int j = 0; j < 8; j++) c[i][j] += a[i] * bb[j];
        }
    }

#pragma unroll
    for (int i = 0; i < 8; i++) {
        int m = m0 + ty * 8 + i;
        if (m < M) {
            size_t rowoff;
            if (FC1MAP) { int tt = m >> 5, bb2 = m & 31; rowoff = ((size_t)bb2 * T_ + tt) * (size_t)ldc; }
            else        rowoff = (size_t)m * (size_t)ldc;
#pragma unroll
            for (int j = 0; j < 8; j += 4) {
                int n = n0 + tx * 8 + j;
                float4 v;
                v.x = c[i][j + 0] + bias[n + 0];
                v.y = c[i][j + 1] + bias[n + 1];
                v.z = c[i][j + 2] + bias[n + 2];
                v.w = c[i][j + 3] + bias[n + 3];
                *(float4*)(C + rowoff + n) = v;
            }
        }
    }
}

// ---------------------------------------------------------------------------
// PERSISTENT bi-GRU encoder: 128 blocks; rotating h; per-dir 64-block barrier.
// ---------------------------------------------------------------------------
__global__ __launch_bounds__(256)
void enc_coop_kernel(const float* __restrict__ gxf, const float* __restrict__ gxb,
                     const float* __restrict__ Whh_f, const float* __restrict__ bhh_f,
                     const float* __restrict__ Whh_b, const float* __restrict__ bhh_b,
                     float* __restrict__ encrot, float* __restrict__ enc_bt,
                     const float* __restrict__ fcW, const float* __restrict__ fcb,
                     float* __restrict__ hT0, unsigned* __restrict__ bars)
{
    const int bid = blockIdx.x;
    const int dir = bid >> 6, bh = (bid >> 5) & 1, kc = bid & 31;
    const int tid = threadIdx.x;
    const int bl = tid & 15, kl = tid >> 4;
    const int b = bh * 16 + bl, k = kc * 16 + kl;
    const float* Whh = dir ? Whh_b : Whh_f;
    const float* bhhp = dir ? bhh_b : bhh_f;
    const float* gx  = dir ? gxb : gxf;
    __shared__ float hL[16 * 516];
    const float* wr = Whh + (size_t)k * H_;
    const float* wz = Whh + (size_t)(H_ + k) * H_;
    const float* wn = Whh + (size_t)(2 * H_ + k) * H_;
    const float b_r = bhhp[k], b_z = bhhp[H_ + k], b_n = bhhp[2 * H_ + k];
    unsigned* dbar = bars + dir * 512;
    const int idx = bid & 63;

    for (int t = 0; t < S_; ++t) {
        const float* hin = encrot + (size_t)t * (2 * B_ * H_) + (size_t)dir * (B_ * H_);
        float* hout = encrot + (size_t)(t + 1) * (2 * B_ * H_) + (size_t)dir * (B_ * H_);
        const float* hsrc = hin + (size_t)bh * 16 * H_;
        for (int i = tid * 4; i < 16 * H_; i += 1024) {
            int r = i >> 9, cix = i & 511;
            *(float4*)&hL[r * 516 + cix] = *(const float4*)(hsrc + i);   // cached
        }
        __syncthreads();
        float ar = 0.f, az = 0.f, an = 0.f;
        const float* hv = &hL[bl * 516];
#pragma unroll 4
        for (int j = 0; j < H_; j += 4) {
            float4 h4 = *(const float4*)(hv + j);
            float4 r4 = *(const float4*)(wr + j);
            float4 z4 = *(const float4*)(wz + j);
            float4 n4 = *(const float4*)(wn + j);
            ar += h4.x * r4.x + h4.y * r4.y + h4.z * r4.z + h4.w * r4.w;
            az += h4.x * z4.x + h4.y * z4.y + h4.z * z4.z + h4.w * z4.w;
            an += h4.x * n4.x + h4.y * n4.y + h4.z * n4.z + h4.w * n4.w;
        }
        const float* gxr = gx + ((size_t)t * B_ + b) * G3_;
        float xr = gxr[k], xz = gxr[H_ + k], xn = gxr[2 * H_ + k];
        float rg = 1.f / (1.f + expf(-(xr + ar + b_r)));
        float zg = 1.f / (1.f + expf(-(xz + az + b_z)));
        float ng = tanhf(xn + rg * (an + b_n));
        float hp = hL[bl * 516 + k];
        float h2 = (1.f - zg) * ng + zg * hp;
        ato_stf(hout + (size_t)b * H_ + k, h2);
        int s_out = dir ? (S_ - 1 - t) : t;
        enc_bt[((size_t)b * S_ + s_out) * (2 * H_) + dir * H_ + k] = h2;
        fast_barN(dbar, idx, 4);
    }
    fast_barN(bars + 1024, bid, 8);    // both dirs done

    // tail: hidden = tanh([hf,hb] @ fcW.T + fcb) -> hT0[k*32+b]
    {
        const int b2 = bid & 31, ih = bid >> 5;
        float* hc = hL;
        const float* hfin = encrot + (size_t)S_ * (2 * B_ * H_);
        const float* hf  = hfin + (size_t)b2 * H_;
        const float* hbk = hfin + (size_t)B_ * H_ + (size_t)b2 * H_;
        for (int i = tid; i < H_; i += 256) { hc[i] = hf[i]; hc[H_ + i] = hbk[i]; }
        __syncthreads();
        if (tid < 128) {
            int i = ih * 128 + tid;
            const float* w = fcW + (size_t)i * (2 * H_);
            float acc = 0.f;
            for (int j = 0; j < 2 * H_; j += 4) {
                float4 a4 = *(const float4*)&hc[j];
                float4 w4 = *(const float4*)(w + j);
                acc += a4.x * w4.x + a4.y * w4.y + a4.z * w4.z + a4.w * w4.w;
            }
            ato_stf(hT0 + (size_t)i * B_ + b2, tanhf(acc + fcb[i]));
        }
    }
}

// ---------------------------------------------------------------------------
// PERSISTENT attention decoder v7: 128 blocks, 3 phases/step.
// P0: hwh distributed (4 k/block, 8KB weights) -> hwhB[b][k] (contiguous read)
// P1: attn (blocks 0..31; reads hwh contiguous, streams proj/enc_bt)
//     ghh (blocks 32..127; 16 rows each, coalesced h reads)
// P2: Wih.w k-sliced + gate finish.
// Comm buffers rotate per step: agent stores, plain cached coalesced reads.
// Layouts: h [k][b], hwhB [b][k], wT [c][b], ghh [r][b].
// ---------------------------------------------------------------------------
__global__ __launch_bounds__(256)
void dec_coop_kernel(const float* __restrict__ attn_W, const float* __restrict__ attn_v,
                     const float* __restrict__ enc_projB, const float* __restrict__ enc_bt,
                     const int* __restrict__ src,
                     const float* __restrict__ dWhh, const float* __restrict__ dbhh,
                     const float* __restrict__ dWih, const float* __restrict__ gx_emb,
                     float* __restrict__ cat, float* __restrict__ hrot,
                     float* __restrict__ hwhrot, float* __restrict__ wrot,
                     float* __restrict__ grot, unsigned* __restrict__ bars)
{
    const int bid = blockIdx.x, tid = threadIdx.x;
    __shared__ float smem[4352];   // P0 part[256][5] | attn 1154 | ghh part[256][17] | P2 part[256][13]
    const int b = tid & 31, cc = tid >> 5;
    const int kbase = bid * 4;
    const float* whr0 = attn_W + (size_t)(kbase + 0) * G3_;   // W_h rows (cols 0..512)
    const float* whr1 = attn_W + (size_t)(kbase + 1) * G3_;
    const float* whr2 = attn_W + (size_t)(kbase + 2) * G3_;
    const float* whr3 = attn_W + (size_t)(kbase + 3) * G3_;
    const float* wir0 = dWih + (size_t)(kbase + 0) * DIN_ + E_;
    const float* wir1 = dWih + (size_t)(kbase + 1) * DIN_ + E_;
    const float* wir2 = dWih + (size_t)(kbase + 2) * DIN_ + E_;
    const float* wir3 = dWih + (size_t)(kbase + 3) * DIN_ + E_;
    const float* wiz0 = dWih + (size_t)(H_ + kbase + 0) * DIN_ + E_;
    const float* wiz1 = dWih + (size_t)(H_ + kbase + 1) * DIN_ + E_;
    const float* wiz2 = dWih + (size_t)(H_ + kbase + 2) * DIN_ + E_;
    const float* wiz3 = dWih + (size_t)(H_ + kbase + 3) * DIN_ + E_;
    const float* win0 = dWih + (size_t)(2 * H_ + kbase + 0) * DIN_ + E_;
    const float* win1 = dWih + (size_t)(2 * H_ + kbase + 1) * DIN_ + E_;
    const float* win2 = dWih + (size_t)(2 * H_ + kbase + 2) * DIN_ + E_;
    const float* win3 = dWih + (size_t)(2 * H_ + kbase + 3) * DIN_ + E_;

    for (int t = 0; t < TD_; ++t) {
        const float* h_t = hrot + (size_t)t * (H_ * B_);
        float* h_n = hrot + (size_t)(t + 1) * (H_ * B_);
        float* hwh_t = hwhrot + (size_t)t * (H_ * B_);
        float* wT = wrot + (size_t)t * (2 * H_ * B_);
        float* gh = grot + (size_t)t * (G3_ * B_);
        float* cat_t = cat + (size_t)t * B_ * CATK_;

        // ---- P0: hwhB[b][kbase+k4] (thread (b,cc) partial, LDS combine) ----
        {
            float s0 = 0.f, s1 = 0.f, s2 = 0.f, s3 = 0.f;
            const int j0 = cc * 64;
            for (int j = j0; j < j0 + 64; ++j) {
                float hv = h_t[(size_t)j * B_ + b];   // cached, coalesced over b
                s0 += hv * whr0[j]; s1 += hv * whr1[j];
                s2 += hv * whr2[j]; s3 += hv * whr3[j];
            }
            float* part = smem;
            part[tid * 5 + 0] = s0; part[tid * 5 + 1] = s1;
            part[tid * 5 + 2] = s2; part[tid * 5 + 3] = s3;
            __syncthreads();
            if (tid < 128) {
                int bb = tid & 31, k4 = tid >> 5;
                float acc = 0.f;
#pragma unroll
                for (int c2 = 0; c2 < 8; c2++) acc += part[(c2 * 32 + bb) * 5 + k4];
                ato_stf(hwh_t + (size_t)bb * H_ + kbase + k4, acc);
            }
        }
        fast_barN(bars, bid, 8);

        // ---- P1: attn (0..31) | ghh (32..127) ----
        if (bid < 32) {
            const int ab = bid;
            float* hwh = smem;           // 512
            float* vL  = smem + 512;     // 512
            float* aL  = smem + 1024;    // 128
            float* red = smem + 1152;    // 2
            for (int i = tid; i < H_; i += 256) {
                hwh[i] = hwh_t[(size_t)ab * H_ + i];   // contiguous cached
                vL[i]  = attn_v[i];
            }
            __syncthreads();
            int wv = tid >> 6, lane = tid & 63;
            for (int so = 0; so < 32; so++) {
                int s = so * 4 + wv;
                const float* pr = enc_projB + ((size_t)ab * S_ + s) * H_;
                float acc = 0.f;
#pragma unroll
                for (int u = 0; u < 8; u++) {
                    int hh = u * 64 + lane;
                    float x = hwh[hh] + pr[hh];
                    float e2 = __expf(2.f * x);
                    acc += vL[hh] * (1.f - 2.f / (e2 + 1.f));
                }
#pragma unroll
                for (int off = 1; off < 64; off <<= 1) acc += __shfl_xor(acc, off);
                if (lane == 0) aL[s] = acc;
            }
            __syncthreads();
            if (tid < S_) aL[tid] = (src[ab * S_ + tid] != 0) ? aL[tid] : -1e10f;
            __syncthreads();
            if (tid < 64) {
                float m = fmaxf(aL[tid], aL[tid + 64]);
#pragma unroll
                for (int off = 1; off < 64; off <<= 1) m = fmaxf(m, __shfl_xor(m, off));
                if (tid == 0) red[0] = m;
            }
            __syncthreads();
            if (tid < S_) aL[tid] = expf(aL[tid] - red[0]);
            __syncthreads();
            if (tid < 64) {
                float sv = aL[tid] + aL[tid + 64];
#pragma unroll
                for (int off = 1; off < 64; off <<= 1) sv += __shfl_xor(sv, off);
                if (tid == 0) red[1] = sv;
            }
            __syncthreads();
            if (tid < S_) aL[tid] = aL[tid] / red[1];
            __syncthreads();
            const float* eb = enc_bt + (size_t)ab * S_ * (2 * H_) + tid * 4;
            float w0 = 0, w1 = 0, w2 = 0, w3 = 0;
            for (int s = 0; s < S_; s++) {
                float a = aL[s];
                float4 v = *(const float4*)(eb + (size_t)s * (2 * H_));
                w0 += a * v.x; w1 += a * v.y; w2 += a * v.z; w3 += a * v.w;
            }
            float4 outv; outv.x = w0; outv.y = w1; outv.z = w2; outv.w = w3;
            *(float4*)(cat_t + (size_t)ab * CATK_ + (H_ + E_) + tid * 4) = outv;
            ato_stf(wT + (size_t)(tid * 4 + 0) * B_ + ab, w0);
            ato_stf(wT + (size_t)(tid * 4 + 1) * B_ + ab, w1);
            ato_stf(wT + (size_t)(tid * 4 + 2) * B_ + ab, w2);
            ato_stf(wT + (size_t)(tid * 4 + 3) * B_ + ab, w3);
        } else {
            const int r0base = (bid - 32) * 16;
            float acc[16];
#pragma unroll
            for (int r = 0; r < 16; ++r) acc[r] = 0.f;
            for (int jj = 0; jj < 16; ++jj) {
                int j = cc * 64 + jj * 4;
                float h0 = h_t[(size_t)(j + 0) * B_ + b];   // cached, coalesced
                float h1 = h_t[(size_t)(j + 1) * B_ + b];
                float h2v = h_t[(size_t)(j + 2) * B_ + b];
                float h3 = h_t[(size_t)(j + 3) * B_ + b];
#pragma unroll
                for (int r = 0; r < 16; ++r) {
                    float4 w = *(const float4*)(dWhh + (size_t)(r0base + r) * H_ + j);
                    acc[r] += h0 * w.x + h1 * w.y + h2v * w.z + h3 * w.w;
                }
            }
            float* part = smem;   // [256][17]
#pragma unroll
            for (int r = 0; r < 16; ++r) part[tid * 17 + r] = acc[r];
            __syncthreads();
            for (int o = tid; o < 512; o += 256) {
                int r = o >> 5, bb = o & 31;
                float s = 0.f;
#pragma unroll
                for (int c2 = 0; c2 < 8; ++c2) s += part[(c2 * 32 + bb) * 17 + r];
                ato_stf(gh + (size_t)(r0base + r) * B_ + bb, s + dbhh[r0base + r]);
            }
        }
        fast_barN(bars, bid, 8);

        // ---- P2: xw = Wih.w (thread (b,cc) partial) + gate finish ----
        {
            float s[12];
#pragma unroll
            for (int i = 0; i < 12; i++) s[i] = 0.f;
            const int c0 = cc * 128;
            for (int c = c0; c < c0 + 128; ++c) {
                float wv = wT[(size_t)c * B_ + b];   // cached, coalesced over b
                s[0]  += wv * wir0[c]; s[1]  += wv * wiz0[c]; s[2]  += wv * win0[c];
                s[3]  += wv * wir1[c]; s[4]  += wv * wiz1[c]; s[5]  += wv * win1[c];
                s[6]  += wv * wir2[c]; s[7]  += wv * wiz2[c]; s[8]  += wv * win2[c];
                s[9]  += wv * wir3[c]; s[10] += wv * wiz3[c]; s[11] += wv * win3[c];
            }
            float* part = smem;   // [256][13]
#pragma unroll
            for (int i = 0; i < 12; i++) part[tid * 13 + i] = s[i];
            __syncthreads();
            if (tid < 128) {
                int bb = tid & 31, k4 = tid >> 5;
                int k = kbase + k4;
                float xr = 0.f, xz = 0.f, xn = 0.f;
#pragma unroll
                for (int c2 = 0; c2 < 8; ++c2) {
                    int pi = (c2 * 32 + bb) * 13 + k4 * 3;
                    xr += part[pi + 0]; xz += part[pi + 1]; xn += part[pi + 2];
                }
                float hr = gh[(size_t)k * B_ + bb];
                float hz = gh[(size_t)(H_ + k) * B_ + bb];
                float hn = gh[(size_t)(2 * H_ + k) * B_ + bb];
                const float* gxe = gx_emb + ((size_t)t * B_ + bb) * G3_;
                float rg = 1.f / (1.f + expf(-(gxe[k] + xr + hr)));
                float zg = 1.f / (1.f + expf(-(gxe[H_ + k] + xz + hz)));
                float ng = tanhf(gxe[2 * H_ + k] + xn + rg * hn);
                float hp = h_t[(size_t)k * B_ + bb];
                float h2 = (1.f - zg) * ng + zg * hp;
                ato_stf(h_n + (size_t)k * B_ + bb, h2);
                cat_t[(size_t)bb * CATK_ + k] = h2;
            }
        }
        fast_barN(bars, bid, 8);
    }
}

// ---------------------------------------------------------------------------
__global__ __launch_bounds__(256)
void splitA_kernel(const float* __restrict__ cat,
                   unsigned short* __restrict__ Ahi, unsigned short* __restrict__ Alo)
{
    size_t i4 = ((size_t)blockIdx.x * 256 + threadIdx.x) * 4;
    if (i4 >= (size_t)MPAD_ * CATK_) return;
    size_t row = i4 / CATK_;
    float4 v;
    if (row < (size_t)TD_ * B_) v = *(const float4*)(cat + i4);
    else { v.x = v.y = v.z = v.w = 0.f; }
    float f[4] = {v.x, v.y, v.z, v.w};
    unsigned short h[4], l[4];
#pragma unroll
    for (int j = 0; j < 4; j++) {
        h[j] = bf16_rne(f[j]);
        float hf = __uint_as_float((unsigned)h[j] << 16);
        l[j] = bf16_rne(f[j] - hf);
    }
    *(ushort4*)(Ahi + i4) = make_ushort4(h[0], h[1], h[2], h[3]);
    *(ushort4*)(Alo + i4) = make_ushort4(l[0], l[1], l[2], l[3]);
}

// ---------------------------------------------------------------------------
__global__ __launch_bounds__(256)
void fc1_mfma_kernel(const unsigned short* __restrict__ Ahi,
                     const unsigned short* __restrict__ Alo,
                     const float* __restrict__ W,
                     const float* __restrict__ bias,
                     float* __restrict__ C)
{
    __shared__ unsigned short lA[2][128][40];
    __shared__ unsigned short lW[2][128][40];
    const int tid = threadIdx.x;
    const int m0 = blockIdx.x * 128, n0 = blockIdx.y * 128;
    const int w = tid >> 6, lane = tid & 63;
    const int wm = w >> 1, wn = w & 1;
    const int frow = lane & 15, fk = (lane >> 4) * 8;

    f32x4 acc[4][4];
#pragma unroll
    for (int mi = 0; mi < 4; mi++)
#pragma unroll
        for (int ni = 0; ni < 4; ni++) acc[mi][ni] = (f32x4){0.f, 0.f, 0.f, 0.f};

    const int srow = tid >> 1;
    const int skq = (tid & 1) * 16;

    const unsigned short* gAhi = Ahi + (size_t)(m0 + srow) * CATK_ + skq;
    const unsigned short* gAlo = Alo + (size_t)(m0 + srow) * CATK_ + skq;
    const float*          gW   = W   + (size_t)(n0 + srow) * CATK_ + skq;

    int4 rAh0, rAh1, rAl0, rAl1;
    float4 rW0, rW1, rW2, rW3;

#define FC1_LOAD(kb)                                        \
    do {                                                    \
        rAh0 = *(const int4*)(gAhi + (kb));                 \
        rAh1 = *(const int4*)(gAhi + (kb) + 8);             \
        rAl0 = *(const int4*)(gAlo + (kb));                 \
        rAl1 = *(const int4*)(gAlo + (kb) + 8);             \
        rW0  = *(const float4*)(gW + (kb));                 \
        rW1  = *(const float4*)(gW + (kb) + 4);             \
        rW2  = *(const float4*)(gW + (kb) + 8);             \
        rW3  = *(const float4*)(gW + (kb) + 12);            \
    } while (0)

    FC1_LOAD(0);

    for (int kb = 0; kb < CATK_; kb += 32) {
        __syncthreads();
        *(int4*)&lA[0][srow][skq]     = rAh0;
        *(int4*)&lA[0][srow][skq + 8] = rAh1;
        *(int4*)&lA[1][srow][skq]     = rAl0;
        *(int4*)&lA[1][srow][skq + 8] = rAl1;
        {
            float f[16] = {rW0.x, rW0.y, rW0.z, rW0.w, rW1.x, rW1.y, rW1.z, rW1.w,
                           rW2.x, rW2.y, rW2.z, rW2.w, rW3.x, rW3.y, rW3.z, rW3.w};
            unsigned hp[8], lp[8];
#pragma unroll
            for (int j = 0; j < 8; j++) {
                float x0 = f[2 * j], x1 = f[2 * j + 1];
                unsigned short h0 = bf16_rne(x0), h1 = bf16_rne(x1);
                float r0 = x0 - __uint_as_float((unsigned)h0 << 16);
                float r1 = x1 - __uint_as_float((unsigned)h1 << 16);
                hp[j] = (unsigned)h0 | ((unsigned)h1 << 16);
                lp[j] = (unsigned)bf16_rne(r0) | ((unsigned)bf16_rne(r1) << 16);
            }
            *(int4*)&lW[0][srow][skq]     = make_int4(hp[0], hp[1], hp[2], hp[3]);
            *(int4*)&lW[0][srow][skq + 8] = make_int4(hp[4], hp[5], hp[6], hp[7]);
            *(int4*)&lW[1][srow][skq]     = make_int4(lp[0], lp[1], lp[2], lp[3]);
            *(int4*)&lW[1][srow][skq + 8] = make_int4(lp[4], lp[5], lp[6], lp[7]);
        }
        __syncthreads();
        if (kb + 32 < CATK_) FC1_LOAD(kb + 32);

        bf16x8 a[2][4];
#pragma unroll
        for (int mi = 0; mi < 4; mi++) {
            int r = wm * 64 + mi * 16 + frow;
            a[0][mi] = *(const bf16x8*)&lA[0][r][fk];
            a[1][mi] = *(const bf16x8*)&lA[1][r][fk];
        }
#pragma unroll
        for (int ni = 0; ni < 4; ni++) {
            int r = wn * 64 + ni * 16 + frow;
            bf16x8 bh = *(const bf16x8*)&lW[0][r][fk];
            bf16x8 bl = *(const bf16x8*)&lW[1][r][fk];
#pragma unroll
            for (int mi = 0; mi < 4; mi++) {
                acc[mi][ni] = __builtin_amdgcn_mfma_f32_16x16x32_bf16(a[0][mi], bh, acc[mi][ni], 0, 0, 0);
                acc[mi][ni] = __builtin_amdgcn_mfma_f32_16x16x32_bf16(a[1][mi], bh, acc[mi][ni], 0, 0, 0);
                acc[mi][ni] = __builtin_amdgcn_mfma_f32_16x16x32_bf16(a[0][mi], bl, acc[mi][ni], 0, 0, 0);
            }
        }
    }
#undef FC1_LOAD

#pragma unroll
    for (int ni = 0; ni < 4; ni++) {
        int col = n0 + wn * 64 + ni * 16 + frow;
        float bc = bias[col];
#pragma unroll
        for (int mi = 0; mi < 4; mi++) {
            int mbase = m0 + wm * 64 + mi * 16 + (lane >> 4) * 4;
            f32x4 v = acc[mi][ni];
#pragma unroll
            for (int r = 0; r < 4; r++) {
                int m = mbase + r;
                if (m < TD_ * B_) {
                    int tt = m >> 5, bb2 = m & 31;
                    C[((size_t)bb2 * T_ + tt) * V_ + col] = v[r] + bc;
                }
            }
        }
    }
}

// ---------------------------------------------------------------------------
__global__ __launch_bounds__(256)
void argmax_kernel(const float* __restrict__ outp, float* __restrict__ preds)
{
    int row = blockIdx.x;
    int t = row >> 5, b = row & 31;
    const float* p = outp + ((size_t)b * T_ + t) * V_;
    int tid = threadIdx.x;
    float best = -3.4e38f; int bi = V_;
    for (int i = tid; i < V_; i += 256) {
        float v = p[i];
        if (v > best) { best = v; bi = i; }
    }
    __shared__ float bv[256];
    __shared__ int bidx[256];
    bv[tid] = best; bidx[tid] = bi;
    __syncthreads();
    for (int off = 128; off > 0; off >>= 1) {
        if (tid < off) {
            float v2 = bv[tid + off]; int i2 = bidx[tid + off];
            if (v2 > bv[tid] || (v2 == bv[tid] && i2 < bidx[tid])) { bv[tid] = v2; bidx[tid] = i2; }
        }
        __syncthreads();
    }
    if (tid == 0) preds[(size_t)b * T_ + t] = (float)bidx[0];
}

// ---------------------------------------------------------------------------
__global__ __launch_bounds__(256)
void zero_tail_kernel(float* __restrict__ outp, float* __restrict__ preds)
{
    int tid = blockIdx.x * 256 + threadIdx.x;
    if (tid < B_ * V_) {
        int b = tid / V_;
        int c = tid % V_;
        outp[((size_t)b * T_ + (T_ - 1)) * V_ + c] = 0.f;
    }
    if (tid < B_) preds[(size_t)tid * T_ + (T_ - 1)] = 0.f;
}

// ---------------------------------------------------------------------------
extern "C" void kernel_launch(void* const* d_in, const int* in_sizes, int n_in,
                              void* d_out, int out_size, void* d_ws, size_t ws_size,
                              hipStream_t stream)
{
    (void)in_sizes; (void)n_in; (void)out_size;
    const int*   src     = (const int*)d_in[0];
    const int*   tgt     = (const int*)d_in[1];
    const float* enc_emb = (const float*)d_in[2];
    const float* Wih_f   = (const float*)d_in[3];
    const float* Whh_f   = (const float*)d_in[4];
    const float* bih_f   = (const float*)d_in[5];
    const float* bhh_f   = (const float*)d_in[6];
    const float* Wih_b   = (const float*)d_in[7];
    const float* Whh_b   = (const float*)d_in[8];
    const float* bih_b   = (const float*)d_in[9];
    const float* bhh_b   = (const float*)d_in[10];
    const float* fcW     = (const float*)d_in[11];
    const float* fcb     = (const float*)d_in[12];
    const float* dec_emb = (const float*)d_in[13];
    const float* attn_W  = (const float*)d_in[14];
    const float* attn_b  = (const float*)d_in[15];
    const float* attn_v  = (const float*)d_in[16];
    const float* dWih    = (const float*)d_in[17];
    const float* dWhh    = (const float*)d_in[18];
    const float* dbih    = (const float*)d_in[19];
    const float* dbhh    = (const float*)d_in[20];
    const float* fc1W    = (const float*)d_in[21];
    const float* fc1b    = (const float*)d_in[22];
    (void)dbih;

    // ws layout
    float* ws     = (float*)d_ws;
    float* cat    = ws;                                  // 3,612,672 f
    float* gx_emb = cat + (size_t)TD_ * B_ * CATK_;      // 3,096,576 f
    int*   tokf   = (int*)(gx_emb + (size_t)TD_ * B_ * G3_);
    int*   tokb   = tokf + 4096;
    int*   tokd   = tokb + 4096;
    unsigned* bars = (unsigned*)(tokd + 4096);           // 4096 u, 256B-aligned
    unsigned short* Ahi = (unsigned short*)(bars + 4096);
    unsigned short* Alo = Ahi + (size_t)MPAD_ * CATK_;
    size_t ws_req = (size_t)((char*)(Alo + (size_t)MPAD_ * CATK_) - (char*)d_ws);
    const bool use_mfma = (ws_size >= ws_req);

    // d_out scratch (fully overwritten by fc1 + zero_tail afterwards)
    float* dout      = (float*)d_out;
    float* gxf       = dout;                                        // 6,291,456
    float* gxb       = gxf + (size_t)S_ * B_ * G3_;                 // 6,291,456
    float* enc_bt    = gxb + (size_t)S_ * B_ * G3_;                 // 4,194,304
    float* enc_projB = enc_bt + (size_t)B_ * S_ * 2 * H_;           // 2,097,152
    float* hrot      = enc_projB + (size_t)B_ * S_ * H_;            // 64 x 16,384
    float* hwhrot    = hrot + (size_t)64 * H_ * B_;                 // 64 x 16,384
    float* wrot      = hwhrot + (size_t)64 * H_ * B_;               // 64 x 32,768
    float* grot      = wrot + (size_t)64 * 2 * H_ * B_;             // 64 x 49,152
    float* encrot    = grot + (size_t)64 * G3_ * B_;                // 129 x 32,768
    float* preds     = dout + (size_t)B_ * T_ * V_;

    dim3 thr(256);

    hipLaunchKernelGGL(prep_kernel, dim3(256), thr, 0, stream,
                       src, tgt, tokf, tokb, tokd, encrot, bars);
    hipLaunchKernelGGL(emb_cat_kernel, dim3(TD_ * B_), thr, 0, stream, tokd, dec_emb, cat);

    hipLaunchKernelGGL((gemm128_kernel<1, 0>), dim3(G3_ / 128, (S_ * B_) / 128), thr, 0, stream,
                       (const float*)nullptr, 0, tokf, enc_emb, Wih_f, E_, bih_f,
                       gxf, G3_, S_ * B_, G3_, E_);
    hipLaunchKernelGGL((gemm128_kernel<1, 0>), dim3(G3_ / 128, (S_ * B_) / 128), thr, 0, stream,
                       (const float*)nullptr, 0, tokb, enc_emb, Wih_b, E_, bih_b,
                       gxb, G3_, S_ * B_, G3_, E_);

    hipLaunchKernelGGL(enc_coop_kernel, dim3(128), thr, 0, stream,
                       gxf, gxb, Whh_f, bhh_f, Whh_b, bhh_b, encrot, enc_bt,
                       fcW, fcb, hrot /* h slot 0 */, bars);

    hipLaunchKernelGGL((gemm128_kernel<0, 0>), dim3(H_ / 128, (B_ * S_) / 128), thr, 0, stream,
                       enc_bt, 2 * H_, (const int*)nullptr, (const float*)nullptr,
                       attn_W + H_, G3_, attn_b, enc_projB, H_, B_ * S_, H_, 2 * H_);

    hipLaunchKernelGGL((gemm128_kernel<1, 0>), dim3(G3_ / 128, (TD_ * B_ + 127) / 128), thr, 0, stream,
                       (const float*)nullptr, 0, tokd, dec_emb, dWih, DIN_, dbih,
                       gx_emb, G3_, TD_ * B_, G3_, E_);

    hipLaunchKernelGGL(dec_coop_kernel, dim3(128), thr, 0, stream,
                       attn_W, attn_v, enc_projB, enc_bt, src,
                       dWhh, dbhh, dWih, gx_emb, cat, hrot, hwhrot, wrot, grot,
                       bars + 2048);

    if (use_mfma) {
        hipLaunchKernelGGL(splitA_kernel, dim3((MPAD_ * CATK_ / 4 + 255) / 256), thr, 0, stream,
                           cat, Ahi, Alo);
        hipLaunchKernelGGL(fc1_mfma_kernel, dim3(MPAD_ / 128, V_ / 128), thr, 0, stream,
                           Ahi, Alo, fc1W, fc1b, dout);
    } else {
        hipLaunchKernelGGL((gemm128_kernel<0, 1>), dim3(V_ / 128, (TD_ * B_ + 127) / 128), thr, 0, stream,
                           cat, CATK_, (const int*)nullptr, (const float*)nullptr,
                           fc1W, CATK_, fc1b, dout, V_, TD_ * B_, V_, CATK_);
    }

    hipLaunchKernelGGL(argmax_kernel, dim3(TD_ * B_), thr, 0, stream, dout, preds);
    hipLaunchKernelGGL(zero_tail_kernel, dim3((B_ * V_ + 255) / 256), thr, 0, stream, dout, preds);
}

// Round 8
// 8702.219 us; speedup vs baseline: 1.2641x; 1.2033x over previous
//
#include <hip/hip_runtime.h>

#define V_ 32000
#define E_ 256
#define H_ 512
#define B_ 32
#define S_ 128
#define T_ 64
#define TD_ 63        // decoder steps (T-1)
#define G3_ 1536      // 3*H
#define CATK_ 1792    // H + E + 2H
#define DIN_ 1280     // E + 2H
#define MPAD_ 2048    // padded M for fc1 MFMA
#define MBS_ 4096     // B_*S_ (P_ihw minor dim)

typedef __attribute__((ext_vector_type(8))) short bf16x8;
typedef __attribute__((ext_vector_type(4))) float f32x4;

__device__ inline unsigned short bf16_rne(float x) {
    unsigned u = __float_as_uint(x);
    unsigned r = u + 0x7FFFu + ((u >> 16) & 1u);
    return (unsigned short)(r >> 16);
}

// agent-scope ops: bypass stale caches, no invalidation (r5-proven fast path)
__device__ __forceinline__ float ato_ldf(const float* p) {
    return __hip_atomic_load((const float*)p, __ATOMIC_RELAXED, __HIP_MEMORY_SCOPE_AGENT);
}
__device__ __forceinline__ void ato_stf(float* p, float v) {
    __hip_atomic_store(p, v, __ATOMIC_RELAXED, __HIP_MEMORY_SCOPE_AGENT);
}

// ---------------------------------------------------------------------------
// Fence-free hierarchical barrier: groups of 16 blocks + top level.
// ---------------------------------------------------------------------------
__device__ __forceinline__ void fast_barN(unsigned* base, int idx, unsigned ngroups)
{
    asm volatile("s_waitcnt vmcnt(0)" ::: "memory");
    __syncthreads();
    if (threadIdx.x == 0) {
        unsigned* gcnt = base + (idx >> 4) * 64;
        unsigned* ggen = gcnt + 32;
        unsigned* tcnt = base + ngroups * 64;
        unsigned* tgen = tcnt + 32;
        unsigned g0 = __hip_atomic_load(ggen, __ATOMIC_RELAXED, __HIP_MEMORY_SCOPE_AGENT);
        unsigned a  = __hip_atomic_fetch_add(gcnt, 1u, __ATOMIC_RELAXED, __HIP_MEMORY_SCOPE_AGENT);
        if (a == 15u) {
            unsigned t0 = __hip_atomic_load(tgen, __ATOMIC_RELAXED, __HIP_MEMORY_SCOPE_AGENT);
            unsigned ta = __hip_atomic_fetch_add(tcnt, 1u, __ATOMIC_RELAXED, __HIP_MEMORY_SCOPE_AGENT);
            if (ta == ngroups - 1u) {
                __hip_atomic_store(tcnt, 0u, __ATOMIC_RELAXED, __HIP_MEMORY_SCOPE_AGENT);
                __hip_atomic_store(tgen, t0 + 1u, __ATOMIC_RELAXED, __HIP_MEMORY_SCOPE_AGENT);
            } else {
                while (__hip_atomic_load(tgen, __ATOMIC_RELAXED, __HIP_MEMORY_SCOPE_AGENT) == t0)
                    __builtin_amdgcn_s_sleep(1);
            }
            __hip_atomic_store(gcnt, 0u, __ATOMIC_RELAXED, __HIP_MEMORY_SCOPE_AGENT);
            __hip_atomic_store(ggen, g0 + 1u, __ATOMIC_RELAXED, __HIP_MEMORY_SCOPE_AGENT);
        } else {
            while (__hip_atomic_load(ggen, __ATOMIC_RELAXED, __HIP_MEMORY_SCOPE_AGENT) == g0)
                __builtin_amdgcn_s_sleep(1);
        }
    }
    __syncthreads();
}

// ---------------------------------------------------------------------------
__global__ __launch_bounds__(256)
void prep_kernel(const int* __restrict__ src, const int* __restrict__ tgt,
                 int* __restrict__ tokf, int* __restrict__ tokb, int* __restrict__ tokd,
                 float* __restrict__ enc_h0, unsigned* __restrict__ bars)
{
    int tid = blockIdx.x * 256 + threadIdx.x;
    if (tid < S_ * B_) {
        int s = tid >> 5, b = tid & 31;
        tokf[tid] = src[b * S_ + s];
        tokb[tid] = src[b * S_ + (S_ - 1 - s)];
    }
    if (tid < TD_ * B_) {
        int t = tid >> 5, b = tid & 31;
        tokd[tid] = tgt[b * T_ + t];
    }
    if (tid < 2 * B_ * H_) enc_h0[tid] = 0.f;   // encrot slot 0
    if (tid < 4096) bars[tid] = 0u;
}

// ---------------------------------------------------------------------------
__global__ __launch_bounds__(256)
void emb_cat_kernel(const int* __restrict__ tokd, const float* __restrict__ dec_emb,
                    float* __restrict__ cat)
{
    int row = blockIdx.x;          // row = t*32 + b
    int tid = threadIdx.x;         // 0..255 == E_
    cat[(size_t)row * CATK_ + H_ + tid] = dec_emb[(size_t)tokd[row] * E_ + tid];
}

// ---------------------------------------------------------------------------
// Generic fp32 GEMM (small GEMMs + fallback fc1)
// ---------------------------------------------------------------------------
template<int GATHER, int FC1MAP>
__global__ __launch_bounds__(256)
void gemm128_kernel(const float* __restrict__ A, int lda,
                    const int* __restrict__ tokens, const float* __restrict__ emb,
                    const float* __restrict__ W, int ldw,
                    const float* __restrict__ bias,
                    float* __restrict__ C, int ldc,
                    int M, int N, int K)
{
    __shared__ float As[16][132];
    __shared__ float Ws[16][132];
    (void)N;
    int tid = threadIdx.x;
    int m0 = blockIdx.y * 128, n0 = blockIdx.x * 128;
    int tx = tid & 15, ty = tid >> 4;
    float c[8][8];
#pragma unroll
    for (int i = 0; i < 8; i++)
#pragma unroll
        for (int j = 0; j < 8; j++) c[i][j] = 0.f;

    int arow = tid >> 1;
    int kq = (tid & 1) * 8;

    int am = m0 + arow; if (am >= M) am = M - 1;
    const float* arp;
    if (GATHER) arp = emb + (size_t)tokens[am] * (size_t)K;
    else        arp = A + (size_t)am * (size_t)lda;
    const float* wrp = W + (size_t)(n0 + arow) * (size_t)ldw;

    for (int kb = 0; kb < K; kb += 16) {
        __syncthreads();
        float4 a0 = *(const float4*)(arp + kb + kq);
        float4 a1 = *(const float4*)(arp + kb + kq + 4);
        float4 w0 = *(const float4*)(wrp + kb + kq);
        float4 w1 = *(const float4*)(wrp + kb + kq + 4);
        As[kq + 0][arow] = a0.x; As[kq + 1][arow] = a0.y;
        As[kq + 2][arow] = a0.z; As[kq + 3][arow] = a0.w;
        As[kq + 4][arow] = a1.x; As[kq + 5][arow] = a1.y;
        As[kq + 6][arow] = a1.z; As[kq + 7][arow] = a1.w;
        Ws[kq + 0][arow] = w0.x; Ws[kq + 1][arow] = w0.y;
        Ws[kq + 2][arow] = w0.z; Ws[kq + 3][arow] = w0.w;
        Ws[kq + 4][arow] = w1.x; Ws[kq + 5][arow] = w1.y;
        Ws[kq + 6][arow] = w1.z; Ws[kq + 7][arow] = w1.w;
        __syncthreads();
#pragma unroll
        for (int kk = 0; kk < 16; kk++) {
            float a[8], bb[8];
            *(float4*)&a[0]  = *(const float4*)&As[kk][ty * 8];
            *(float4*)&a[4]  = *(const float4*)&As[kk][ty * 8 + 4];
            *(float4*)&bb[0] = *(const float4*)&Ws[kk][tx * 8];
            *(float4*)&bb[4] = *(const float4*)&Ws[kk][tx * 8 + 4];
#pragma unroll
            for (int i = 0; i < 8; i++)
#pragma unroll
                for (int j = 0; j < 8; j++) c[i][j] += a[i] * bb[j];
        }
    }

#pragma unroll
    for (int i = 0; i < 8; i++) {
        int m = m0 + ty * 8 + i;
        if (m < M) {
            size_t rowoff;
            if (FC1MAP) { int tt = m >> 5, bb2 = m & 31; rowoff = ((size_t)bb2 * T_ + tt) * (size_t)ldc; }
            else        rowoff = (size_t)m * (size_t)ldc;
#pragma unroll
            for (int j = 0; j < 8; j += 4) {
                int n = n0 + tx * 8 + j;
                float4 v;
                v.x = c[i][j + 0] + bias[n + 0];
                v.y = c[i][j + 1] + bias[n + 1];
                v.z = c[i][j + 2] + bias[n + 2];
                v.w = c[i][j + 3] + bias[n + 3];
                *(float4*)(C + rowoff + n) = v;
            }
        }
    }
}

// ---------------------------------------------------------------------------
// PERSISTENT bi-GRU encoder (unchanged from r7): rotating h, cached reads,
// agent stores, per-dir 64-block barrier. Tail -> hT slot 0 ([k*32+b]).
// ---------------------------------------------------------------------------
__global__ __launch_bounds__(256)
void enc_coop_kernel(const float* __restrict__ gxf, const float* __restrict__ gxb,
                     const float* __restrict__ Whh_f, const float* __restrict__ bhh_f,
                     const float* __restrict__ Whh_b, const float* __restrict__ bhh_b,
                     float* __restrict__ encrot, float* __restrict__ enc_bt,
                     const float* __restrict__ fcW, const float* __restrict__ fcb,
                     float* __restrict__ hT0, unsigned* __restrict__ bars)
{
    const int bid = blockIdx.x;
    const int dir = bid >> 6, bh = (bid >> 5) & 1, kc = bid & 31;
    const int tid = threadIdx.x;
    const int bl = tid & 15, kl = tid >> 4;
    const int b = bh * 16 + bl, k = kc * 16 + kl;
    const float* Whh = dir ? Whh_b : Whh_f;
    const float* bhhp = dir ? bhh_b : bhh_f;
    const float* gx  = dir ? gxb : gxf;
    __shared__ float hL[16 * 516];
    const float* wr = Whh + (size_t)k * H_;
    const float* wz = Whh + (size_t)(H_ + k) * H_;
    const float* wn = Whh + (size_t)(2 * H_ + k) * H_;
    const float b_r = bhhp[k], b_z = bhhp[H_ + k], b_n = bhhp[2 * H_ + k];
    unsigned* dbar = bars + dir * 512;
    const int idx = bid & 63;

    for (int t = 0; t < S_; ++t) {
        const float* hin = encrot + (size_t)t * (2 * B_ * H_) + (size_t)dir * (B_ * H_);
        float* hout = encrot + (size_t)(t + 1) * (2 * B_ * H_) + (size_t)dir * (B_ * H_);
        const float* hsrc = hin + (size_t)bh * 16 * H_;
        for (int i = tid * 4; i < 16 * H_; i += 1024) {
            int r = i >> 9, cix = i & 511;
            *(float4*)&hL[r * 516 + cix] = *(const float4*)(hsrc + i);
        }
        __syncthreads();
        float ar = 0.f, az = 0.f, an = 0.f;
        const float* hv = &hL[bl * 516];
#pragma unroll 4
        for (int j = 0; j < H_; j += 4) {
            float4 h4 = *(const float4*)(hv + j);
            float4 r4 = *(const float4*)(wr + j);
            float4 z4 = *(const float4*)(wz + j);
            float4 n4 = *(const float4*)(wn + j);
            ar += h4.x * r4.x + h4.y * r4.y + h4.z * r4.z + h4.w * r4.w;
            az += h4.x * z4.x + h4.y * z4.y + h4.z * z4.z + h4.w * z4.w;
            an += h4.x * n4.x + h4.y * n4.y + h4.z * n4.z + h4.w * n4.w;
        }
        const float* gxr = gx + ((size_t)t * B_ + b) * G3_;
        float xr = gxr[k], xz = gxr[H_ + k], xn = gxr[2 * H_ + k];
        float rg = 1.f / (1.f + expf(-(xr + ar + b_r)));
        float zg = 1.f / (1.f + expf(-(xz + az + b_z)));
        float ng = tanhf(xn + rg * (an + b_n));
        float hp = hL[bl * 516 + k];
        float h2 = (1.f - zg) * ng + zg * hp;
        ato_stf(hout + (size_t)b * H_ + k, h2);
        int s_out = dir ? (S_ - 1 - t) : t;
        enc_bt[((size_t)b * S_ + s_out) * (2 * H_) + dir * H_ + k] = h2;
        fast_barN(dbar, idx, 4);
    }
    fast_barN(bars + 1024, bid, 8);    // both dirs done

    // tail: hidden = tanh([hf,hb] @ fcW.T + fcb) -> hT0[k*32+b]
    {
        const int b2 = bid & 31, ih = bid >> 5;
        float* hc = hL;
        const float* hfin = encrot + (size_t)S_ * (2 * B_ * H_);
        const float* hf  = hfin + (size_t)b2 * H_;
        const float* hbk = hfin + (size_t)B_ * H_ + (size_t)b2 * H_;
        for (int i = tid; i < H_; i += 256) { hc[i] = hf[i]; hc[H_ + i] = hbk[i]; }
        __syncthreads();
        if (tid < 128) {
            int i = ih * 128 + tid;
            const float* w = fcW + (size_t)i * (2 * H_);
            float acc = 0.f;
            for (int j = 0; j < 2 * H_; j += 4) {
                float4 a4 = *(const float4*)&hc[j];
                float4 w4 = *(const float4*)(w + j);
                acc += a4.x * w4.x + a4.y * w4.y + a4.z * w4.z + a4.w * w4.w;
            }
            ato_stf(hT0 + (size_t)i * B_ + b2, tanhf(acc + fcb[i]));
        }
    }
}

// ---------------------------------------------------------------------------
// PERSISTENT attention decoder v8: 64 blocks, 3 phases/step.
// P0 (all 64): read full h once -> hwh (8 rows/block) + ghh (24 rows/block).
// P1: attn (blocks 0..31): scores+softmax -> aLrot[t]. blocks 32..63 idle.
// P2 (all 64): xw[k] = sum_s aL[b][s]*P_ihw[row][b*S+s] for 8 k x 3 gates +
//              gate finish -> h', cat.  (Wih.w folded into precomputed P_ihw.)
// Comm (h, hwh, ghh, aL) via agent atomics on FIXED buffers (r5 fast path).
// Layouts: hT [pp][k*32+b], hwhT [b][k], ghh [r*32+b], aLrot [t][b][s].
// ---------------------------------------------------------------------------
__global__ __launch_bounds__(256)
void dec_coop_kernel(const float* __restrict__ attn_W, const float* __restrict__ attn_v,
                     const float* __restrict__ enc_projB, const int* __restrict__ src,
                     const float* __restrict__ dWhh, const float* __restrict__ dbhh,
                     const float* __restrict__ P_ihw, const float* __restrict__ gx_emb,
                     float* __restrict__ cat, float* __restrict__ hT,
                     float* __restrict__ hwhT, float* __restrict__ ghh,
                     float* __restrict__ aLrot, unsigned* __restrict__ bars)
{
    const int bid = blockIdx.x, tid = threadIdx.x;
    __shared__ float smem[256 * 33];   // P0 part(33-stride) | attn bufs | P2 part(25-stride)
    const int b = tid & 31, cc = tid >> 5;
    const int kb8 = bid * 8;    // hwh + P2 k ownership
    const int gb24 = bid * 24;  // ghh row ownership

    for (int t = 0; t < TD_; ++t) {
        const int pp = t & 1;
        const float* hin = hT + (size_t)pp * (H_ * B_);
        float* hnext = hT + (size_t)(1 - pp) * (H_ * B_);
        float* aLt = aLrot + (size_t)t * (B_ * S_);
        float* cat_t = cat + (size_t)t * B_ * CATK_;

        // ---- P0: hwh (8 rows) + ghh (24 rows); h read ONCE per block ----
        {
            float s[32];
#pragma unroll
            for (int i = 0; i < 32; i++) s[i] = 0.f;
            const int j0 = cc * 64;
            for (int jj = 0; jj < 64; jj += 4) {
                const int j = j0 + jj;
                float h0 = ato_ldf(hin + (size_t)(j + 0) * B_ + b);
                float h1 = ato_ldf(hin + (size_t)(j + 1) * B_ + b);
                float h2v = ato_ldf(hin + (size_t)(j + 2) * B_ + b);
                float h3 = ato_ldf(hin + (size_t)(j + 3) * B_ + b);
#pragma unroll
                for (int r = 0; r < 8; r++) {
                    float4 w = *(const float4*)(attn_W + (size_t)(kb8 + r) * G3_ + j);
                    s[r] += h0 * w.x + h1 * w.y + h2v * w.z + h3 * w.w;
                }
#pragma unroll
                for (int r = 0; r < 24; r++) {
                    float4 w = *(const float4*)(dWhh + (size_t)(gb24 + r) * H_ + j);
                    s[8 + r] += h0 * w.x + h1 * w.y + h2v * w.z + h3 * w.w;
                }
            }
#pragma unroll
            for (int i = 0; i < 32; i++) smem[tid * 33 + i] = s[i];
            __syncthreads();
            {
                int r8 = tid >> 5, bb = tid & 31;
                float acc = 0.f;
#pragma unroll
                for (int c2 = 0; c2 < 8; c2++) acc += smem[(c2 * 32 + bb) * 33 + r8];
                ato_stf(hwhT + (size_t)bb * H_ + kb8 + r8, acc);
#pragma unroll
                for (int i = 0; i < 3; i++) {
                    int o = i * 256 + tid;
                    int r = o >> 5, b2 = o & 31;
                    float a = 0.f;
#pragma unroll
                    for (int c2 = 0; c2 < 8; c2++) a += smem[(c2 * 32 + b2) * 33 + 8 + r];
                    ato_stf(ghh + (size_t)(gb24 + r) * B_ + b2, a + dbhh[gb24 + r]);
                }
            }
        }
        fast_barN(bars, bid, 4);

        // ---- P1: attention (blocks 0..31) -> aLrot[t]; others idle ----
        if (bid < 32) {
            const int ab = bid;
            float* hwh = smem;           // 512
            float* vL  = smem + 512;     // 512
            float* aLs = smem + 1024;    // 128
            float* red = smem + 1152;    // 2
            for (int i = tid; i < H_; i += 256) {
                hwh[i] = ato_ldf(hwhT + (size_t)ab * H_ + i);
                vL[i]  = attn_v[i];
            }
            __syncthreads();
            int wv = tid >> 6, lane = tid & 63;
            for (int so = 0; so < 32; so++) {
                int s = so * 4 + wv;
                const float* pr = enc_projB + ((size_t)ab * S_ + s) * H_;
                float acc = 0.f;
#pragma unroll
                for (int u = 0; u < 8; u++) {
                    int hh = u * 64 + lane;
                    float x = hwh[hh] + pr[hh];
                    float e2 = __expf(2.f * x);
                    acc += vL[hh] * (1.f - 2.f / (e2 + 1.f));
                }
#pragma unroll
                for (int off = 1; off < 64; off <<= 1) acc += __shfl_xor(acc, off);
                if (lane == 0) aLs[s] = acc;
            }
            __syncthreads();
            if (tid < S_) aLs[tid] = (src[ab * S_ + tid] != 0) ? aLs[tid] : -1e10f;
            __syncthreads();
            if (tid < 64) {
                float m = fmaxf(aLs[tid], aLs[tid + 64]);
#pragma unroll
                for (int off = 1; off < 64; off <<= 1) m = fmaxf(m, __shfl_xor(m, off));
                if (tid == 0) red[0] = m;
            }
            __syncthreads();
            if (tid < S_) aLs[tid] = expf(aLs[tid] - red[0]);
            __syncthreads();
            if (tid < 64) {
                float sv = aLs[tid] + aLs[tid + 64];
#pragma unroll
                for (int off = 1; off < 64; off <<= 1) sv += __shfl_xor(sv, off);
                if (tid == 0) red[1] = sv;
            }
            __syncthreads();
            if (tid < S_) ato_stf(aLt + (size_t)ab * S_ + tid, aLs[tid] / red[1]);
        }
        fast_barN(bars, bid, 4);

        // ---- P2: xw from P_ihw + gates ----
        {
            float s2[24];
#pragma unroll
            for (int i = 0; i < 24; i++) s2[i] = 0.f;
            const int s0 = cc * 16;
            float al[16];
#pragma unroll
            for (int i = 0; i < 16; i++)
                al[i] = ato_ldf(aLt + (size_t)b * S_ + s0 + i);
#pragma unroll
            for (int g = 0; g < 3; g++) {
#pragma unroll
                for (int r = 0; r < 8; r++) {
                    const float* pr = P_ihw + (size_t)(g * H_ + kb8 + r) * MBS_ + (size_t)b * S_ + s0;
                    float acc = 0.f;
#pragma unroll
                    for (int i = 0; i < 16; i += 4) {
                        float4 p = *(const float4*)(pr + i);
                        acc += al[i] * p.x + al[i + 1] * p.y + al[i + 2] * p.z + al[i + 3] * p.w;
                    }
                    s2[g * 8 + r] = acc;
                }
            }
#pragma unroll
            for (int i = 0; i < 24; i++) smem[tid * 25 + i] = s2[i];
            __syncthreads();
            {
                int k4 = tid >> 5, bb = tid & 31;
                int k = kb8 + k4;
                float xr = 0.f, xz = 0.f, xn = 0.f;
#pragma unroll
                for (int c2 = 0; c2 < 8; c2++) {
                    int pi = (c2 * 32 + bb) * 25;
                    xr += smem[pi + k4];
                    xz += smem[pi + 8 + k4];
                    xn += smem[pi + 16 + k4];
                }
                float hr = ato_ldf(ghh + (size_t)k * B_ + bb);
                float hz = ato_ldf(ghh + (size_t)(H_ + k) * B_ + bb);
                float hn = ato_ldf(ghh + (size_t)(2 * H_ + k) * B_ + bb);
                const float* gxe = gx_emb + ((size_t)t * B_ + bb) * G3_;
                float rg = 1.f / (1.f + expf(-(gxe[k] + xr + hr)));
                float zg = 1.f / (1.f + expf(-(gxe[H_ + k] + xz + hz)));
                float ng = tanhf(gxe[2 * H_ + k] + xn + rg * hn);
                float hp = ato_ldf(hin + (size_t)k * B_ + bb);
                float h2 = (1.f - zg) * ng + zg * hp;
                ato_stf(hnext + (size_t)k * B_ + bb, h2);
                cat_t[(size_t)bb * CATK_ + k] = h2;
            }
        }
        fast_barN(bars, bid, 4);
    }
}

// ---------------------------------------------------------------------------
// reconstruct weighted vectors into cat[:, 768:1792] from stored aL
// grid = 512: (b 32, dc 16 chunks of 64 dims)
// ---------------------------------------------------------------------------
__global__ __launch_bounds__(256)
void wcat_kernel(const float* __restrict__ aLrot, const float* __restrict__ enc_bt,
                 float* __restrict__ cat)
{
    const int b = blockIdx.x & 31, dc = blockIdx.x >> 5;
    const int d0 = dc * 64;
    const int tid = threadIdx.x;
    __shared__ float ebt[128 * 64];
    __shared__ float aLs[128];
    __shared__ float partw[256];
    for (int i = tid; i < 128 * 16; i += 256) {
        int s = i >> 4, dq = (i & 15) * 4;
        float4 v = *(const float4*)(enc_bt + ((size_t)b * S_ + s) * (2 * H_) + d0 + dq);
        *(float4*)&ebt[s * 64 + dq] = v;
    }
    __syncthreads();
    for (int t = 0; t < TD_; t++) {
        if (tid < 128) aLs[tid] = aLrot[((size_t)t * B_ + b) * S_ + tid];
        __syncthreads();
        int d = tid & 63, sg = tid >> 6;
        float acc = 0.f;
        for (int s = sg * 32; s < sg * 32 + 32; s++) acc += aLs[s] * ebt[s * 64 + d];
        partw[tid] = acc;
        __syncthreads();
        if (tid < 64) {
            float w = partw[tid] + partw[tid + 64] + partw[tid + 128] + partw[tid + 192];
            cat[((size_t)t * B_ + b) * CATK_ + H_ + E_ + d0 + tid] = w;
        }
        __syncthreads();
    }
}

// ---------------------------------------------------------------------------
// split fp32 -> bf16 hi/lo (trailing region beyond `valid` zero-padded)
// ---------------------------------------------------------------------------
__global__ __launch_bounds__(256)
void split_kernel(const float* __restrict__ src, unsigned short* __restrict__ hi,
                  unsigned short* __restrict__ lo, long total, long valid)
{
    long i4 = ((long)blockIdx.x * 256 + threadIdx.x) * 4;
    if (i4 >= total) return;
    float4 v;
    if (i4 < valid) v = *(const float4*)(src + i4);
    else { v.x = v.y = v.z = v.w = 0.f; }
    float f[4] = {v.x, v.y, v.z, v.w};
    unsigned short h[4], l[4];
#pragma unroll
    for (int j = 0; j < 4; j++) {
        h[j] = bf16_rne(f[j]);
        float hf = __uint_as_float((unsigned)h[j] << 16);
        l[j] = bf16_rne(f[j] - hf);
    }
    *(ushort4*)(hi + i4) = make_ushort4(h[0], h[1], h[2], h[3]);
    *(ushort4*)(lo + i4) = make_ushort4(l[0], l[1], l[2], l[3]);
}

// ---------------------------------------------------------------------------
// split-bf16 MFMA GEMM (hh+hl+lh == fp32-accurate).
// TRANS=0: fc1 path (bias, t/b-mapped rows, M-guard).  TRANS=1: C[col][m].
// ---------------------------------------------------------------------------
template<int KLEN, int TRANS>
__global__ __launch_bounds__(256)
void mfma_gemm_kernel(const unsigned short* __restrict__ Ahi,
                      const unsigned short* __restrict__ Alo,
                      const float* __restrict__ W, int ldw,
                      const float* __restrict__ bias,
                      float* __restrict__ C, int ldc, int Mvalid)
{
    __shared__ unsigned short lA[2][128][40];
    __shared__ unsigned short lW[2][128][40];
    const int tid = threadIdx.x;
    const int m0 = blockIdx.x * 128, n0 = blockIdx.y * 128;
    const int w = tid >> 6, lane = tid & 63;
    const int wm = w >> 1, wn = w & 1;
    const int frow = lane & 15, fk = (lane >> 4) * 8;

    f32x4 acc[4][4];
#pragma unroll
    for (int mi = 0; mi < 4; mi++)
#pragma unroll
        for (int ni = 0; ni < 4; ni++) acc[mi][ni] = (f32x4){0.f, 0.f, 0.f, 0.f};

    const int srow = tid >> 1;
    const int skq = (tid & 1) * 16;

    const unsigned short* gAhi = Ahi + (size_t)(m0 + srow) * KLEN + skq;
    const unsigned short* gAlo = Alo + (size_t)(m0 + srow) * KLEN + skq;
    const float*          gW   = W   + (size_t)(n0 + srow) * ldw + skq;

    int4 rAh0, rAh1, rAl0, rAl1;
    float4 rW0, rW1, rW2, rW3;

#define MG_LOAD(kb)                                         \
    do {                                                    \
        rAh0 = *(const int4*)(gAhi + (kb));                 \
        rAh1 = *(const int4*)(gAhi + (kb) + 8);             \
        rAl0 = *(const int4*)(gAlo + (kb));                 \
        rAl1 = *(const int4*)(gAlo + (kb) + 8);             \
        rW0  = *(const float4*)(gW + (kb));                 \
        rW1  = *(const float4*)(gW + (kb) + 4);             \
        rW2  = *(const float4*)(gW + (kb) + 8);             \
        rW3  = *(const float4*)(gW + (kb) + 12);            \
    } while (0)

    MG_LOAD(0);

    for (int kb = 0; kb < KLEN; kb += 32) {
        __syncthreads();
        *(int4*)&lA[0][srow][skq]     = rAh0;
        *(int4*)&lA[0][srow][skq + 8] = rAh1;
        *(int4*)&lA[1][srow][skq]     = rAl0;
        *(int4*)&lA[1][srow][skq + 8] = rAl1;
        {
            float f[16] = {rW0.x, rW0.y, rW0.z, rW0.w, rW1.x, rW1.y, rW1.z, rW1.w,
                           rW2.x, rW2.y, rW2.z, rW2.w, rW3.x, rW3.y, rW3.z, rW3.w};
            unsigned hp[8], lp[8];
#pragma unroll
            for (int j = 0; j < 8; j++) {
                float x0 = f[2 * j], x1 = f[2 * j + 1];
                unsigned short h0 = bf16_rne(x0), h1 = bf16_rne(x1);
                float r0 = x0 - __uint_as_float((unsigned)h0 << 16);
                float r1 = x1 - __uint_as_float((unsigned)h1 << 16);
                hp[j] = (unsigned)h0 | ((unsigned)h1 << 16);
                lp[j] = (unsigned)bf16_rne(r0) | ((unsigned)bf16_rne(r1) << 16);
            }
            *(int4*)&lW[0][srow][skq]     = make_int4(hp[0], hp[1], hp[2], hp[3]);
            *(int4*)&lW[0][srow][skq + 8] = make_int4(hp[4], hp[5], hp[6], hp[7]);
            *(int4*)&lW[1][srow][skq]     = make_int4(lp[0], lp[1], lp[2], lp[3]);
            *(int4*)&lW[1][srow][skq + 8] = make_int4(lp[4], lp[5], lp[6], lp[7]);
        }
        __syncthreads();
        if (kb + 32 < KLEN) MG_LOAD(kb + 32);

        bf16x8 a[2][4];
#pragma unroll
        for (int mi = 0; mi < 4; mi++) {
            int r = wm * 64 + mi * 16 + frow;
            a[0][mi] = *(const bf16x8*)&lA[0][r][fk];
            a[1][mi] = *(const bf16x8*)&lA[1][r][fk];
        }
#pragma unroll
        for (int ni = 0; ni < 4; ni++) {
            int r = wn * 64 + ni * 16 + frow;
            bf16x8 bh = *(const bf16x8*)&lW[0][r][fk];
            bf16x8 bl = *(const bf16x8*)&lW[1][r][fk];
#pragma unroll
            for (int mi = 0; mi < 4; mi++) {
                acc[mi][ni] = __builtin_amdgcn_mfma_f32_16x16x32_bf16(a[0][mi], bh, acc[mi][ni], 0, 0, 0);
                acc[mi][ni] = __builtin_amdgcn_mfma_f32_16x16x32_bf16(a[1][mi], bh, acc[mi][ni], 0, 0, 0);
                acc[mi][ni] = __builtin_amdgcn_mfma_f32_16x16x32_bf16(a[0][mi], bl, acc[mi][ni], 0, 0, 0);
            }
        }
    }
#undef MG_LOAD

#pragma unroll
    for (int ni = 0; ni < 4; ni++) {
        int col = n0 + wn * 64 + ni * 16 + frow;
        float bc = TRANS ? 0.f : bias[col];
#pragma unroll
        for (int mi = 0; mi < 4; mi++) {
            int mbase = m0 + wm * 64 + mi * 16 + (lane >> 4) * 4;
            f32x4 v = acc[mi][ni];
            if (TRANS) {
                float4 o; o.x = v[0]; o.y = v[1]; o.z = v[2]; o.w = v[3];
                *(float4*)(C + (size_t)col * ldc + mbase) = o;
            } else {
#pragma unroll
                for (int r = 0; r < 4; r++) {
                    int m = mbase + r;
                    if (m < Mvalid) {
                        int tt = m >> 5, bb2 = m & 31;
                        C[((size_t)bb2 * T_ + tt) * ldc + col] = v[r] + bc;
                    }
                }
            }
        }
    }
}

// ---------------------------------------------------------------------------
__global__ __launch_bounds__(256)
void argmax_kernel(const float* __restrict__ outp, float* __restrict__ preds)
{
    int row = blockIdx.x;
    int t = row >> 5, b = row & 31;
    const float* p = outp + ((size_t)b * T_ + t) * V_;
    int tid = threadIdx.x;
    float best = -3.4e38f; int bi = V_;
    for (int i = tid; i < V_; i += 256) {
        float v = p[i];
        if (v > best) { best = v; bi = i; }
    }
    __shared__ float bv[256];
    __shared__ int bidx[256];
    bv[tid] = best; bidx[tid] = bi;
    __syncthreads();
    for (int off = 128; off > 0; off >>= 1) {
        if (tid < off) {
            float v2 = bv[tid + off]; int i2 = bidx[tid + off];
            if (v2 > bv[tid] || (v2 == bv[tid] && i2 < bidx[tid])) { bv[tid] = v2; bidx[tid] = i2; }
        }
        __syncthreads();
    }
    if (tid == 0) preds[(size_t)b * T_ + t] = (float)bidx[0];
}

// ---------------------------------------------------------------------------
__global__ __launch_bounds__(256)
void zero_tail_kernel(float* __restrict__ outp, float* __restrict__ preds)
{
    int tid = blockIdx.x * 256 + threadIdx.x;
    if (tid < B_ * V_) {
        int b = tid / V_;
        int c = tid % V_;
        outp[((size_t)b * T_ + (T_ - 1)) * V_ + c] = 0.f;
    }
    if (tid < B_) preds[(size_t)tid * T_ + (T_ - 1)] = 0.f;
}

// ---------------------------------------------------------------------------
extern "C" void kernel_launch(void* const* d_in, const int* in_sizes, int n_in,
                              void* d_out, int out_size, void* d_ws, size_t ws_size,
                              hipStream_t stream)
{
    (void)in_sizes; (void)n_in; (void)out_size;
    const int*   src     = (const int*)d_in[0];
    const int*   tgt     = (const int*)d_in[1];
    const float* enc_emb = (const float*)d_in[2];
    const float* Wih_f   = (const float*)d_in[3];
    const float* Whh_f   = (const float*)d_in[4];
    const float* bih_f   = (const float*)d_in[5];
    const float* bhh_f   = (const float*)d_in[6];
    const float* Wih_b   = (const float*)d_in[7];
    const float* Whh_b   = (const float*)d_in[8];
    const float* bih_b   = (const float*)d_in[9];
    const float* bhh_b   = (const float*)d_in[10];
    const float* fcW     = (const float*)d_in[11];
    const float* fcb     = (const float*)d_in[12];
    const float* dec_emb = (const float*)d_in[13];
    const float* attn_W  = (const float*)d_in[14];
    const float* attn_b  = (const float*)d_in[15];
    const float* attn_v  = (const float*)d_in[16];
    const float* dWih    = (const float*)d_in[17];
    const float* dWhh    = (const float*)d_in[18];
    const float* dbih    = (const float*)d_in[19];
    const float* dbhh    = (const float*)d_in[20];
    const float* fc1W    = (const float*)d_in[21];
    const float* fc1b    = (const float*)d_in[22];
    (void)dbih;

    // ws layout
    float* ws     = (float*)d_ws;
    float* cat    = ws;                                  // 3,612,672 f
    float* gx_emb = cat + (size_t)TD_ * B_ * CATK_;      // 3,096,576 f
    int*   tokf   = (int*)(gx_emb + (size_t)TD_ * B_ * G3_);
    int*   tokb   = tokf + 4096;
    int*   tokd   = tokb + 4096;
    unsigned* bars = (unsigned*)(tokd + 4096);           // 4096 u, 256B-aligned
    unsigned short* Ahi = (unsigned short*)(bars + 4096);
    unsigned short* Alo = Ahi + (size_t)MPAD_ * CATK_;
    size_t ws_req = (size_t)((char*)(Alo + (size_t)MPAD_ * CATK_) - (char*)d_ws);
    const bool use_mfma = (ws_size >= ws_req);

    // d_out scratch (fully overwritten by fc1 + zero_tail afterwards)
    float* dout      = (float*)d_out;
    float* gxf       = dout;                                        // 6,291,456
    float* gxb       = gxf + (size_t)S_ * B_ * G3_;                 // 6,291,456
    float* enc_bt    = gxb + (size_t)S_ * B_ * G3_;                 // 4,194,304
    float* enc_projB = enc_bt + (size_t)B_ * S_ * 2 * H_;           // 2,097,152
    float* encrot    = enc_projB + (size_t)B_ * S_ * H_;            // 129 x 32,768
    float* hT        = encrot + (size_t)(S_ + 1) * 2 * B_ * H_;     // 2 x 16,384
    float* hwhT      = hT + 2 * H_ * B_;                            // 16,384
    float* ghh       = hwhT + H_ * B_;                              // 49,152
    float* aLrot     = ghh + (size_t)G3_ * B_;                      // 258,048
    float* P_ihw     = aLrot + (size_t)TD_ * B_ * S_;               // 6,291,456
    unsigned short* Bhi = (unsigned short*)(P_ihw + (size_t)G3_ * MBS_);   // 4,194,304 us
    unsigned short* Blo = Bhi + (size_t)MBS_ * 1024;                       // 4,194,304 us
    float* preds     = dout + (size_t)B_ * T_ * V_;

    dim3 thr(256);

    hipLaunchKernelGGL(prep_kernel, dim3(256), thr, 0, stream,
                       src, tgt, tokf, tokb, tokd, encrot, bars);
    hipLaunchKernelGGL(emb_cat_kernel, dim3(TD_ * B_), thr, 0, stream, tokd, dec_emb, cat);

    hipLaunchKernelGGL((gemm128_kernel<1, 0>), dim3(G3_ / 128, (S_ * B_) / 128), thr, 0, stream,
                       (const float*)nullptr, 0, tokf, enc_emb, Wih_f, E_, bih_f,
                       gxf, G3_, S_ * B_, G3_, E_);
    hipLaunchKernelGGL((gemm128_kernel<1, 0>), dim3(G3_ / 128, (S_ * B_) / 128), thr, 0, stream,
                       (const float*)nullptr, 0, tokb, enc_emb, Wih_b, E_, bih_b,
                       gxb, G3_, S_ * B_, G3_, E_);

    // encoder recurrence + enc_fc in ONE launch
    hipLaunchKernelGGL(enc_coop_kernel, dim3(128), thr, 0, stream,
                       gxf, gxb, Whh_f, bhh_f, Whh_b, bhh_b, encrot, enc_bt,
                       fcW, fcb, hT /* slot 0 */, bars);

    hipLaunchKernelGGL((gemm128_kernel<0, 0>), dim3(H_ / 128, (B_ * S_) / 128), thr, 0, stream,
                       enc_bt, 2 * H_, (const int*)nullptr, (const float*)nullptr,
                       attn_W + H_, G3_, attn_b, enc_projB, H_, B_ * S_, H_, 2 * H_);

    hipLaunchKernelGGL((gemm128_kernel<1, 0>), dim3(G3_ / 128, (TD_ * B_ + 127) / 128), thr, 0, stream,
                       (const float*)nullptr, 0, tokd, dec_emb, dWih, DIN_, dbih,
                       gx_emb, G3_, TD_ * B_, G3_, E_);

    // P_ihw = (dWih w-cols) x enc_bt^T  via split-bf16 MFMA  -> [1536][4096]
    hipLaunchKernelGGL(split_kernel, dim3((MBS_ * 1024 / 4 + 255) / 256), thr, 0, stream,
                       enc_bt, Bhi, Blo, (long)MBS_ * 1024, (long)MBS_ * 1024);
    hipLaunchKernelGGL((mfma_gemm_kernel<1024, 1>), dim3(MBS_ / 128, G3_ / 128), thr, 0, stream,
                       Bhi, Blo, dWih + E_, DIN_, (const float*)nullptr,
                       P_ihw, MBS_, MBS_);

    // decoder recurrence in ONE launch (64 blocks)
    hipLaunchKernelGGL(dec_coop_kernel, dim3(64), thr, 0, stream,
                       attn_W, attn_v, enc_projB, src,
                       dWhh, dbhh, P_ihw, gx_emb, cat, hT, hwhT, ghh, aLrot,
                       bars + 2048);

    // reconstruct weighted vectors into cat
    hipLaunchKernelGGL(wcat_kernel, dim3(512), thr, 0, stream, aLrot, enc_bt, cat);

    if (use_mfma) {
        hipLaunchKernelGGL(split_kernel, dim3((MPAD_ * CATK_ / 4 + 255) / 256), thr, 0, stream,
                           cat, Ahi, Alo, (long)MPAD_ * CATK_, (long)TD_ * B_ * CATK_);
        hipLaunchKernelGGL((mfma_gemm_kernel<CATK_, 0>), dim3(MPAD_ / 128, V_ / 128), thr, 0, stream,
                           Ahi, Alo, fc1W, CATK_, fc1b, dout, V_, TD_ * B_);
    } else {
        hipLaunchKernelGGL((gemm128_kernel<0, 1>), dim3(V_ / 128, (TD_ * B_ + 127) / 128), thr, 0, stream,
                           cat, CATK_, (const int*)nullptr, (const float*)nullptr,
                           fc1W, CATK_, fc1b, dout, V_, TD_ * B_, V_, CATK_);
    }

    hipLaunchKernelGGL(argmax_kernel, dim3(TD_ * B_), thr, 0, stream, dout, preds);
    hipLaunchKernelGGL(zero_tail_kernel, dim3((B_ * V_ + 255) / 256), thr, 0, stream, dout, preds);
}